// Round 4
// baseline (880.019 us; speedup 1.0000x reference)
//
#include <hip/hip_runtime.h>

using u16 = unsigned short;
using u32 = unsigned int;

typedef __attribute__((ext_vector_type(8))) short bf16x8;
typedef __attribute__((ext_vector_type(4))) float f32x4;

#define MFMA16 __builtin_amdgcn_mfma_f32_16x16x32_bf16

// ---------- fp32 <-> bf16 hi/lo split helpers ----------
__device__ __forceinline__ u16 f2bf(float f) {
  u32 u = __float_as_uint(f);
  u += 0x7fffu + ((u >> 16) & 1u);   // RNE
  return (u16)(u >> 16);
}
__device__ __forceinline__ float bf2f(u16 h) { return __uint_as_float(((u32)h) << 16); }

// async global->LDS, 16B per lane; LDS dest is wave-uniform base + lane*16
__device__ __forceinline__ void gld16(const u16* g, u16* s) {
  __builtin_amdgcn_global_load_lds((const __attribute__((address_space(1))) u32*)g,
                                   (__attribute__((address_space(3))) u32*)s, 16, 0, 0);
}

struct EpParams {
  const float* bias;
  const float* bias2;      // second-half bias (merged attn)
  const u16* b2;           // second-half B (merged attn)
  const float* bnsc;
  const float* bnsh;
  u16* dhi; u16* dlo; int dstride;
  float* f32a; float* f32b; int f32stride;
  const float* nscale; const float* escale;
};

// ---------------------------------------------------------------------------
// 256x256 8-wave pipelined GEMM (T3+T4+T5), BK=32, TRIPLE-buffered LDS.
// Race-free by construction: staging targets slot (t+2)%3, readers use t%3;
// end-of-iter lgkmcnt(0) + counted vmcnt + barrier close the only hazards.
// LDS is fragment-ordered: both the global_load_lds write and every
// ds_read_b128 are lane-linear => zero bank conflicts.
// EP: 0 = bias->ReLU->BN (hi[+lo])  2 = tanh (B/bias by tm-half)  4 = dec2
// ---------------------------------------------------------------------------
template<int EP, int NM, bool SLO>
__global__ __launch_bounds__(512, 2) void gemm256_k(
    const u16* __restrict__ Ah, const u16* __restrict__ Al, int lda,
    const u16* __restrict__ Bh, int K, int N, EpParams p)
{
  __shared__ __align__(16) u16 sA[3][8192];
  __shared__ __align__(16) u16 sB[3][8192];
  __shared__ __align__(16) u16 sAl[(NM >= 2) ? 3 : 1][8192];

  const int t = threadIdx.x;
  const int lane = t & 63, wid = t >> 6;
  const int wm = wid >> 2, wn = wid & 3;
  const int fr = lane & 15, fg = lane >> 4;
  const int tm = blockIdx.x, tn = blockIdx.y;
  const int NT = K >> 5;

  const u16* BhS = Bh;
  const float* bias = p.bias;
  if constexpr (EP == 2) {
    if (tm >= 32) { BhS = p.b2; bias = p.bias2; }
  }

  const int strow = wid * 16 + fr;
  const u16* gA  = Ah + (size_t)(tm * 256 + strow) * (size_t)lda + fg * 8;
  const u16* gAl = (NM >= 2) ? Al + (size_t)(tm * 256 + strow) * (size_t)lda + fg * 8 : gA;
  const u16* gB  = BhS + (size_t)(tn * 256 + strow) * (size_t)K + fg * 8;

  auto stA = [&](int slot, int c, int k0) {
    gld16(gA + (size_t)c * 128 * lda + k0, &sA[slot][c * 4096 + wid * 512]);
  };
  auto stL = [&](int slot, int c, int k0) {
    gld16(gAl + (size_t)c * 128 * lda + k0, &sAl[slot][c * 4096 + wid * 512]);
  };
  auto stB = [&](int slot, int c, int k0) {
    gld16(gB + (size_t)c * 128 * K + k0, &sB[slot][c * 4096 + wid * 512]);
  };

  f32x4 acc[8][4];
#pragma unroll
  for (int m = 0; m < 8; m++)
#pragma unroll
    for (int n = 0; n < 4; n++) acc[m][n] = f32x4{0.f, 0.f, 0.f, 0.f};

  // ---- prologue: stage K-tiles 0 and 1 ----
  stA(0, 0, 0); stA(0, 1, 0);
  if constexpr (NM >= 2) { stL(0, 0, 0); stL(0, 1, 0); }
  stB(0, 0, 0); stB(0, 1, 0);
  stA(1, 0, 32); stA(1, 1, 32);
  if constexpr (NM >= 2) { stL(1, 0, 32); stL(1, 1, 32); }
  stB(1, 0, 32); stB(1, 1, 32);
  if constexpr (NM >= 2) asm volatile("s_waitcnt vmcnt(6)" ::: "memory");
  else                   asm volatile("s_waitcnt vmcnt(4)" ::: "memory");
  __builtin_amdgcn_s_barrier();
  __builtin_amdgcn_sched_barrier(0);

  for (int tt = 0; tt < NT; ++tt) {
    const int slot = tt % 3;
    const int nsl  = (tt + 2) % 3;
    const int k2   = (tt + 2) << 5;
    const bool SG  = (tt + 2 < NT);
    const u16* sa  = sA[slot];
    const u16* sb  = sB[slot];
    const u16* sal = sAl[(NM >= 2) ? slot : 0];

    bf16x8 bfr[4], ah[4], al[4];
    // -------- phase 0: m = 0..3 --------
#pragma unroll
    for (int n = 0; n < 4; ++n) bfr[n] = *(const bf16x8*)&sb[(wn * 4 + n) * 512 + lane * 8];
#pragma unroll
    for (int m = 0; m < 4; ++m) ah[m] = *(const bf16x8*)&sa[(wm * 8 + m) * 512 + lane * 8];
    if constexpr (NM >= 2) {
#pragma unroll
      for (int m = 0; m < 4; ++m) al[m] = *(const bf16x8*)&sal[(wm * 8 + m) * 512 + lane * 8];
    }
    if (SG) {
      stA(nsl, 0, k2); stA(nsl, 1, k2);
      if constexpr (NM >= 2) stL(nsl, 0, k2);
    }
    __builtin_amdgcn_s_barrier();
    __builtin_amdgcn_sched_barrier(0);
    __builtin_amdgcn_s_setprio(1);
#pragma unroll
    for (int m = 0; m < 4; ++m)
#pragma unroll
      for (int n = 0; n < 4; ++n) {
        if constexpr (NM >= 2) acc[m][n] = MFMA16(al[m], bfr[n], acc[m][n], 0, 0, 0);
        acc[m][n] = MFMA16(ah[m], bfr[n], acc[m][n], 0, 0, 0);
      }
    __builtin_amdgcn_s_setprio(0);
    __builtin_amdgcn_s_barrier();
    __builtin_amdgcn_sched_barrier(0);
    // -------- phase 1: m = 4..7 --------
#pragma unroll
    for (int m = 0; m < 4; ++m) ah[m] = *(const bf16x8*)&sa[(wm * 8 + 4 + m) * 512 + lane * 8];
    if constexpr (NM >= 2) {
#pragma unroll
      for (int m = 0; m < 4; ++m) al[m] = *(const bf16x8*)&sal[(wm * 8 + 4 + m) * 512 + lane * 8];
    }
    if (SG) {
      if constexpr (NM >= 2) stL(nsl, 1, k2);
      stB(nsl, 0, k2); stB(nsl, 1, k2);
    }
    __builtin_amdgcn_s_barrier();
    __builtin_amdgcn_sched_barrier(0);
    __builtin_amdgcn_s_setprio(1);
#pragma unroll
    for (int m = 0; m < 4; ++m)
#pragma unroll
      for (int n = 0; n < 4; ++n) {
        if constexpr (NM >= 2) acc[4 + m][n] = MFMA16(al[m], bfr[n], acc[4 + m][n], 0, 0, 0);
        acc[4 + m][n] = MFMA16(ah[m], bfr[n], acc[4 + m][n], 0, 0, 0);
      }
    __builtin_amdgcn_s_setprio(0);
    asm volatile("s_waitcnt lgkmcnt(0)" ::: "memory");
    __builtin_amdgcn_sched_barrier(0);
    if (SG) {
      if constexpr (NM >= 2) asm volatile("s_waitcnt vmcnt(6)" ::: "memory");
      else                   asm volatile("s_waitcnt vmcnt(4)" ::: "memory");
    } else {
      asm volatile("s_waitcnt vmcnt(0)" ::: "memory");
    }
    __builtin_amdgcn_s_barrier();
    __builtin_amdgcn_sched_barrier(0);
  }

  // ---- epilogue: C/D layout col=lane&15, row=4*(lane>>4)+reg [m89] ----
  const int rowb = tm * 256 + wm * 128;
  const int colb = tn * 256 + wn * 64;
#pragma unroll
  for (int n = 0; n < 4; ++n) {
    const int col = colb + n * 16 + fr;
#pragma unroll
    for (int m = 0; m < 8; ++m) {
#pragma unroll
      for (int r = 0; r < 4; ++r) {
        const int row = rowb + m * 16 + fg * 4 + r;
        float val = acc[m][n][r];
        if constexpr (EP == 0) {
          val += bias[col];
          val = fmaxf(val, 0.f);
          val = val * p.bnsc[col] + p.bnsh[col];
          u16 h = f2bf(val);
          p.dhi[(size_t)row * p.dstride + col] = h;
          if constexpr (SLO)
            p.dlo[(size_t)row * p.dstride + col] = f2bf(val - bf2f(h));
        } else if constexpr (EP == 2) {
          val = tanhf(val + bias[col]);
          p.dhi[(size_t)row * p.dstride + col] = f2bf(val);
        } else {                         // EP==4: dec2 -> scaled edge/node out
          if (col < N) {
            val += bias[col];
            if (col < 900) {
              int rr = col / 30, cc = col - rr * 30;
              float s = 1.f;
              if (rr >= 20 && cc >= 20 && rr <= cc) {
                int i0 = rr - 20, j0 = cc - 20;
                int k = i0 * 10 - ((i0 * (i0 - 1)) >> 1) + (j0 - i0);
                s = p.escale[(size_t)row * 55 + k];
              }
              p.f32a[(size_t)row * 900 + col] = val * s;
            } else {
              int tc = col - 900, rr = tc >> 6;
              float s = (rr >= 20) ? p.nscale[(size_t)row * 10 + (rr - 20)] : 1.f;
              p.f32b[(size_t)row * 1920 + tc] = val * s;
            }
          }
        }
      }
    }
  }
}

// ---------------------------------------------------------------------------
// 128x128 m97-structure GEMM (small/odd shapes).
// NM: 1 = A_h*B_h ; 2 = + A_l*B_h ; 3 = + A_h*B_l
// EP: 0=BN(ReLU)(+SLO)  1=mu/lv  5=merged attn L2 logits
// ---------------------------------------------------------------------------
template<int EP, int NM, bool SLO>
__global__ __launch_bounds__(256, (NM == 1) ? 3 : 2) void gemm_k(
    const u16* __restrict__ Ah, const u16* __restrict__ Al, int lda,
    const u16* __restrict__ Bh, const u16* __restrict__ Bl,
    int K, int N, EpParams p)
{
  __shared__ __align__(16) u16 sAh[4096], sBh[4096];
  __shared__ __align__(16) u16 sAl[(NM >= 2) ? 4096 : 16];
  __shared__ __align__(16) u16 sBl[(NM == 3) ? 4096 : 16];
  const int t = threadIdx.x;
  const int lane = t & 63, wid = t >> 6;
  const int tm = blockIdx.x, tn = blockIdx.y;

  const u16* BhS = Bh;
  if constexpr (EP == 5) { if (tm >= 64) BhS = p.b2; }

  const int rp = t >> 2, sp = t & 3;
  const int rl = (rp & ~1) | ((rp & 1) ^ ((rp >> 2) & 1));
  const int sl = sp ^ (rl & 3);
  const u16* pAh = Ah + (size_t)(tm * 128 + rl) * (size_t)lda + sl * 8;
  const u16* pBh = BhS + (size_t)(tn * 128 + rl) * (size_t)K + sl * 8;
  const u16* pAl = (NM >= 2) ? Al + (size_t)(tm * 128 + rl) * (size_t)lda + sl * 8 : pAh;
  const u16* pBl = (NM == 3) ? Bl + (size_t)(tn * 128 + rl) * (size_t)K + sl * 8 : pBh;
  const size_t aStep = (size_t)64 * (size_t)lda;
  const size_t bStep = (size_t)64 * (size_t)K;

  f32x4 acc[4][4];
#pragma unroll
  for (int m = 0; m < 4; m++)
#pragma unroll
    for (int n = 0; n < 4; n++) acc[m][n] = f32x4{0.f, 0.f, 0.f, 0.f};

  const int fr = lane & 15, fg = lane >> 4;
  const int wm = wid >> 1, wn = wid & 1;

  for (int kk = 0; kk < K; kk += 32) {
    gld16(pAh + kk,          sAh + wid * 512);
    gld16(pAh + aStep + kk,  sAh + 2048 + wid * 512);
    gld16(pBh + kk,          sBh + wid * 512);
    gld16(pBh + bStep + kk,  sBh + 2048 + wid * 512);
    if constexpr (NM >= 2) {
      gld16(pAl + kk,         sAl + wid * 512);
      gld16(pAl + aStep + kk, sAl + 2048 + wid * 512);
    }
    if constexpr (NM == 3) {
      gld16(pBl + kk,         sBl + wid * 512);
      gld16(pBl + bStep + kk, sBl + 2048 + wid * 512);
    }
    __syncthreads();

    bf16x8 a_h[4], b_h[4], a_l[4], b_l[4];
#pragma unroll
    for (int f = 0; f < 4; f++) {
      const int ar = wm * 64 + f * 16 + fr;
      const int br = wn * 64 + f * 16 + fr;
      a_h[f] = *(const bf16x8*)&sAh[(ar * 32 + fg * 8) ^ ((ar & 7) << 3)];
      b_h[f] = *(const bf16x8*)&sBh[(br * 32 + fg * 8) ^ ((br & 7) << 3)];
      if constexpr (NM >= 2) a_l[f] = *(const bf16x8*)&sAl[(ar * 32 + fg * 8) ^ ((ar & 7) << 3)];
      if constexpr (NM == 3) b_l[f] = *(const bf16x8*)&sBl[(br * 32 + fg * 8) ^ ((br & 7) << 3)];
    }
#pragma unroll
    for (int m = 0; m < 4; m++)
#pragma unroll
      for (int n = 0; n < 4; n++) {
        if constexpr (NM == 3)
          acc[m][n] = MFMA16(a_h[m], b_l[n], acc[m][n], 0, 0, 0);
        if constexpr (NM >= 2)
          acc[m][n] = MFMA16(a_l[m], b_h[n], acc[m][n], 0, 0, 0);
        acc[m][n] = MFMA16(a_h[m], b_h[n], acc[m][n], 0, 0, 0);
      }
    __syncthreads();
  }

  const int rowb = tm * 128 + wm * 64;
  const int colb = tn * 128 + wn * 64;
#pragma unroll
  for (int n = 0; n < 4; n++) {
    const int col = colb + n * 16 + fr;
#pragma unroll
    for (int m = 0; m < 4; m++) {
#pragma unroll
      for (int r = 0; r < 4; r++) {
        const int row = rowb + m * 16 + fg * 4 + r;
        float val = acc[m][n][r];
        if constexpr (EP == 0) {
          val += p.bias[col];
          val = fmaxf(val, 0.f);
          val = val * p.bnsc[col] + p.bnsh[col];
          u16 h = f2bf(val);
          p.dhi[(size_t)row * p.dstride + col] = h;
          if constexpr (SLO)
            p.dlo[(size_t)row * p.dstride + col] = f2bf(val - bf2f(h));
        } else if constexpr (EP == 1) {
          val += p.bias[col];
          if (col < 256) {
            p.f32a[(size_t)row * 256 + col] = val;
            u16 h = f2bf(val);
            p.dhi[(size_t)row * 256 + col] = h;
            p.dlo[(size_t)row * 256 + col] = f2bf(val - bf2f(h));
          } else {
            p.f32b[(size_t)row * 256 + (col - 256)] = val;
          }
        } else if constexpr (EP == 5) {  // merged attn L2 logits
          if (tm < 64) {
            if (col < 65) p.f32a[(size_t)row * 65 + col] = val + p.bias[col];
          } else {
            if (col < 90) p.f32b[(size_t)(row - 8192) * 90 + col] = val + p.bias2[col];
          }
        }
      }
    }
  }
}

// ---------- fused input conversion: x -> hi/lo ; optical,log -> hi only ----------
__global__ void conv3(const float* __restrict__ x, const float* __restrict__ opt,
                      const float* __restrict__ lg, u16* __restrict__ xh,
                      u16* __restrict__ xl, u16* __restrict__ oh, u16* __restrict__ lh) {
  const int SEG = 8192 * 1024 / 4;
  int i = blockIdx.x * blockDim.x + threadIdx.x;
  if (i < SEG) {
    float4 v = ((const float4*)x)[i];
    ushort4 hh, ll;
    hh.x = f2bf(v.x); ll.x = f2bf(v.x - bf2f(hh.x));
    hh.y = f2bf(v.y); ll.y = f2bf(v.y - bf2f(hh.y));
    hh.z = f2bf(v.z); ll.z = f2bf(v.z - bf2f(hh.z));
    hh.w = f2bf(v.w); ll.w = f2bf(v.w - bf2f(hh.w));
    ((ushort4*)xh)[i] = hh;
    ((ushort4*)xl)[i] = ll;
  } else if (i < 2 * SEG) {
    int j = i - SEG;
    float4 v = ((const float4*)opt)[j];
    ushort4 hh;
    hh.x = f2bf(v.x); hh.y = f2bf(v.y); hh.z = f2bf(v.z); hh.w = f2bf(v.w);
    ((ushort4*)oh)[j] = hh;
  } else if (i < 3 * SEG) {
    int j = i - 2 * SEG;
    float4 v = ((const float4*)lg)[j];
    ushort4 hh;
    hh.x = f2bf(v.x); hh.y = f2bf(v.y); hh.z = f2bf(v.z); hh.w = f2bf(v.w);
    ((ushort4*)lh)[j] = hh;
  }
}

// ---------- W[K,N] fp32 -> Wt hi(/lo) [.,K] transposed, zero-pad n>=N ----------
__global__ void conv_wT(const float* __restrict__ W, u16* __restrict__ Th,
                        u16* __restrict__ Tl, int K, int N) {
  __shared__ float tile[32][33];
  int k0 = blockIdx.x * 32, n0 = blockIdx.y * 32;
  int tx = threadIdx.x, ty = threadIdx.y;
#pragma unroll
  for (int i = ty; i < 32; i += 8) {
    int n = n0 + tx;
    tile[i][tx] = (n < N) ? W[(size_t)(k0 + i) * N + n] : 0.f;
  }
  __syncthreads();
#pragma unroll
  for (int i = ty; i < 32; i += 8) {
    int n = n0 + i, k = k0 + tx;
    float v = tile[tx][i];
    u16 h = f2bf(v);
    Th[(size_t)n * K + k] = h;
    if (Tl) Tl[(size_t)n * K + k] = f2bf(v - bf2f(h));
  }
}

// ---------- block-diag [Wa(512xNa); Wb(512xNb)] -> Wt [128,1024] hi ----------
__global__ void conv_w2bd(const float* __restrict__ Wa, int Na,
                          const float* __restrict__ Wb, int Nb,
                          u16* __restrict__ Th) {
  int idx = blockIdx.x * blockDim.x + threadIdx.x;
  if (idx >= 128 * 1024) return;
  int n = idx >> 10, k = idx & 1023;
  float v = 0.f;
  if (n < Na) { if (k < 512) v = Wa[(size_t)k * Na + n]; }
  else if (n < Na + Nb) { if (k >= 512) v = Wb[(size_t)(k - 512) * Nb + (n - Na)]; }
  Th[idx] = f2bf(v);
}

// ---------- single prep kernel: BN folds + all bias concats ----------
struct PrepArgs {
  const float *bn1_g, *bn1_b, *bn1_m, *bn1_v, *bn2_g, *bn2_b, *bn2_m, *bn2_v;
  const float *mu_b, *lv_b, *on_b1, *oe_b1, *ln_b1, *le_b1, *on_b2, *oe_b2, *ln_b2, *le_b2;
  float *bn1sc, *bn1sh, *bn2sc, *bn2sh, *bias_mulv, *bias_o1, *bias_l1, *bias_o2, *bias_l2;
};
__global__ void prep_k(PrepArgs a) {
  int i = blockIdx.x * blockDim.x + threadIdx.x;
  if (i < 2048) {
    float s = a.bn1_g[i] * rsqrtf(a.bn1_v[i] + 1e-5f);
    a.bn1sc[i] = s; a.bn1sh[i] = a.bn1_b[i] - a.bn1_m[i] * s;
  } else if (i < 4096) {
    int j = i - 2048;
    float s = a.bn2_g[j] * rsqrtf(a.bn2_v[j] + 1e-5f);
    a.bn2sc[j] = s; a.bn2sh[j] = a.bn2_b[j] - a.bn2_m[j] * s;
  } else if (i < 4608) {
    int j = i - 4096; a.bias_mulv[j] = (j < 256) ? a.mu_b[j] : a.lv_b[j - 256];
  } else if (i < 5632) {
    int j = i - 4608; a.bias_o1[j] = (j < 512) ? a.on_b1[j] : a.oe_b1[j - 512];
  } else if (i < 6656) {
    int j = i - 5632; a.bias_l1[j] = (j < 512) ? a.ln_b1[j] : a.le_b1[j - 512];
  } else if (i < 6721) {
    int j = i - 6656; a.bias_o2[j] = (j < 10) ? a.on_b2[j] : a.oe_b2[j - 10];
  } else if (i < 6811) {
    int j = i - 6721; a.bias_l2[j] = (j < 12) ? a.ln_b2[j] : a.le_b2[j - 12];
  }
}

// ---------- combined double softmax -> per-batch scales ----------
__global__ void softmax_combine(const float* __restrict__ lo, const float* __restrict__ ll,
                                float* __restrict__ nsc, float* __restrict__ esc) {
  int b = blockIdx.x * blockDim.x + threadIdx.x;
  if (b >= 8192) return;
  const float* po = lo + (size_t)b * 65;
  const float* pl = ll + (size_t)b * 90;
  float mo = po[0];
  for (int i = 1; i < 10; i++) mo = fmaxf(mo, po[i]);
  float so = 0.f;
  for (int i = 0; i < 10; i++) so += expf(po[i] - mo);
  float ml = pl[0];
  for (int i = 1; i < 12; i++) ml = fmaxf(ml, pl[i]);
  float sl = 0.f;
  for (int i = 0; i < 12; i++) sl += expf(pl[i] - ml);
  float invn = 1.f / (so * sl);
  for (int i = 0; i < 10; i++)
    nsc[(size_t)b * 10 + i] = expf(po[i] - mo) * expf(pl[i] - ml) * invn;
  const float* qo = po + 10;
  const float* ql = pl + 12;
  float meo = qo[0];
  for (int i = 1; i < 55; i++) meo = fmaxf(meo, qo[i]);
  float seo = 0.f;
  for (int i = 0; i < 55; i++) seo += expf(qo[i] - meo);
  float mel = ql[0];
  for (int i = 1; i < 78; i++) mel = fmaxf(mel, ql[i]);
  float sel = 0.f;
  for (int i = 0; i < 78; i++) sel += expf(ql[i] - mel);
  float inve = 1.f / (seo * sel);
  for (int k = 0; k < 55; k++)
    esc[(size_t)b * 55 + k] = expf(qo[k] - meo) * expf(ql[k] - mel) * inve;
}

// ---------------------------------------------------------------------------
extern "C" void kernel_launch(void* const* d_in, const int* in_sizes, int n_in,
                              void* d_out, int out_size, void* d_ws, size_t ws_size,
                              hipStream_t stream) {
  const float* x       = (const float*)d_in[0];
  const float* optical = (const float*)d_in[1];
  const float* logx    = (const float*)d_in[2];
  const float* enc_W   = (const float*)d_in[3];
  const float* enc_b   = (const float*)d_in[4];
  const float* bn1_g   = (const float*)d_in[5];
  const float* bn1_b   = (const float*)d_in[6];
  const float* bn1_m   = (const float*)d_in[7];
  const float* bn1_v   = (const float*)d_in[8];
  const float* mu_W    = (const float*)d_in[9];
  const float* mu_b    = (const float*)d_in[10];
  const float* lv_W    = (const float*)d_in[11];
  const float* lv_b    = (const float*)d_in[12];
  const float* dec_W1  = (const float*)d_in[13];
  const float* dec_b1  = (const float*)d_in[14];
  const float* bn2_g   = (const float*)d_in[15];
  const float* bn2_b   = (const float*)d_in[16];
  const float* bn2_m   = (const float*)d_in[17];
  const float* bn2_v   = (const float*)d_in[18];
  const float* dec_W2  = (const float*)d_in[19];
  const float* dec_b2  = (const float*)d_in[20];
  const float* on_W1   = (const float*)d_in[21];
  const float* on_b1   = (const float*)d_in[22];
  const float* on_W2   = (const float*)d_in[23];
  const float* on_b2   = (const float*)d_in[24];
  const float* oe_W1   = (const float*)d_in[25];
  const float* oe_b1   = (const float*)d_in[26];
  const float* oe_W2   = (const float*)d_in[27];
  const float* oe_b2   = (const float*)d_in[28];
  const float* ln_W1   = (const float*)d_in[29];
  const float* ln_b1   = (const float*)d_in[30];
  const float* ln_W2   = (const float*)d_in[31];
  const float* ln_b2   = (const float*)d_in[32];
  const float* le_W1   = (const float*)d_in[33];
  const float* le_b1   = (const float*)d_in[34];
  const float* le_W2   = (const float*)d_in[35];
  const float* le_b2   = (const float*)d_in[36];

  const int B = 8192;
  float* out_edge = (float*)d_out;
  float* out_node = out_edge + (size_t)B * 900;
  float* out_mu   = out_node + (size_t)B * 1920;
  float* out_lv   = out_mu + (size_t)B * 256;

  // ---- workspace carve ----
  char* base = (char*)d_ws;
  size_t off = 0;
  auto takeB = [&](size_t elems) -> u16* {
    u16* p = (u16*)(base + off);
    off = (off + elems * 2 + 255) & ~(size_t)255;
    return p;
  };
  auto takeF = [&](size_t elems) -> float* {
    float* p = (float*)(base + off);
    off = (off + elems * 4 + 255) & ~(size_t)255;
    return p;
  };
  u16* wEncH  = takeB(2048 * 1024);
  u16* wMulvH = takeB(512 * 2048);   u16* wMulvL = takeB(512 * 2048);
  u16* wDec1H = takeB(2048 * 256);   u16* wDec1L = takeB(2048 * 256);
  u16* wDec2H = takeB(3072 * 2048);                 // padded to 3072 rows
  u16* wO1H   = takeB(1024 * 1024);
  u16* wL1H   = takeB(1024 * 1024);
  u16* wO2H   = takeB(128 * 1024);
  u16* wL2H   = takeB(128 * 1024);
  u16* aXh = takeB((size_t)B * 1024); u16* aXl = takeB((size_t)B * 1024);
  u16* aOLh = takeB((size_t)2 * B * 1024);          // [16384,1024]: opt | log
  u16* aOh = aOLh;
  u16* aLh = aOLh + (size_t)B * 1024;
  u16* aHh = takeB((size_t)B * 2048); u16* aHl = takeB((size_t)B * 2048);
  u16* aZh = takeB((size_t)B * 256);  u16* aZl = takeB((size_t)B * 256);
  u16* aTh = takeB((size_t)2 * B * 1024);           // [16384,1024] tanh out
  float* logitsO = takeF((size_t)B * 65);
  float* logitsL = takeF((size_t)B * 90);
  float* nsc = takeF((size_t)B * 10);
  float* esc = takeF((size_t)B * 55);
  float* bn1sc = takeF(2048); float* bn1sh = takeF(2048);
  float* bn2sc = takeF(2048); float* bn2sh = takeF(2048);
  float* bias_mulv = takeF(512);
  float* bias_o1 = takeF(1024);
  float* bias_l1 = takeF(1024);
  float* bias_o2 = takeF(65);
  float* bias_l2 = takeF(90);

  // ---- prep ----
  PrepArgs pa;
  pa.bn1_g = bn1_g; pa.bn1_b = bn1_b; pa.bn1_m = bn1_m; pa.bn1_v = bn1_v;
  pa.bn2_g = bn2_g; pa.bn2_b = bn2_b; pa.bn2_m = bn2_m; pa.bn2_v = bn2_v;
  pa.mu_b = mu_b; pa.lv_b = lv_b;
  pa.on_b1 = on_b1; pa.oe_b1 = oe_b1; pa.ln_b1 = ln_b1; pa.le_b1 = le_b1;
  pa.on_b2 = on_b2; pa.oe_b2 = oe_b2; pa.ln_b2 = ln_b2; pa.le_b2 = le_b2;
  pa.bn1sc = bn1sc; pa.bn1sh = bn1sh; pa.bn2sc = bn2sc; pa.bn2sh = bn2sh;
  pa.bias_mulv = bias_mulv; pa.bias_o1 = bias_o1; pa.bias_l1 = bias_l1;
  pa.bias_o2 = bias_o2; pa.bias_l2 = bias_l2;
  prep_k<<<27, 256, 0, stream>>>(pa);

  conv3<<<24576, 256, 0, stream>>>(x, optical, logx, aXh, aXl, aOh, aLh);

  dim3 tb(32, 8);
  conv_wT<<<dim3(32, 64), tb, 0, stream>>>(enc_W, wEncH, nullptr, 1024, 2048);
  conv_wT<<<dim3(64, 8), tb, 0, stream>>>(mu_W, wMulvH, wMulvL, 2048, 256);
  conv_wT<<<dim3(64, 8), tb, 0, stream>>>(
      lv_W, wMulvH + (size_t)256 * 2048, wMulvL + (size_t)256 * 2048, 2048, 256);
  conv_wT<<<dim3(8, 64), tb, 0, stream>>>(dec_W1, wDec1H, wDec1L, 256, 2048);
  conv_wT<<<dim3(64, 96), tb, 0, stream>>>(dec_W2, wDec2H, nullptr, 2048, 2820);
  conv_wT<<<dim3(32, 16), tb, 0, stream>>>(on_W1, wO1H, nullptr, 1024, 512);
  conv_wT<<<dim3(32, 16), tb, 0, stream>>>(oe_W1, wO1H + (size_t)512 * 1024, nullptr, 1024, 512);
  conv_wT<<<dim3(32, 16), tb, 0, stream>>>(ln_W1, wL1H, nullptr, 1024, 512);
  conv_wT<<<dim3(32, 16), tb, 0, stream>>>(le_W1, wL1H + (size_t)512 * 1024, nullptr, 1024, 512);
  conv_w2bd<<<512, 256, 0, stream>>>(on_W2, 10, oe_W2, 55, wO2H);
  conv_w2bd<<<512, 256, 0, stream>>>(ln_W2, 12, le_W2, 78, wL2H);

  EpParams p;

  // ---- encode [256² pipeline, NM=2] ----
  p = EpParams{};
  p.bias = enc_b; p.bnsc = bn1sc; p.bnsh = bn1sh;
  p.dhi = aHh; p.dlo = aHl; p.dstride = 2048;
  gemm256_k<0, 2, true><<<dim3(32, 8), 512, 0, stream>>>(
      aXh, aXl, 1024, wEncH, 1024, 2048, p);

  // ---- mu | logvar [128², NM=3] ----
  p = EpParams{};
  p.bias = bias_mulv; p.f32a = out_mu; p.f32b = out_lv;
  p.dhi = aZh; p.dlo = aZl; p.dstride = 256;
  gemm_k<1, 3, false><<<dim3(64, 4), 256, 0, stream>>>(
      aHh, aHl, 2048, wMulvH, wMulvL, 2048, 512, p);

  // ---- decode1 [128², NM=3, hi-only] ----
  p = EpParams{};
  p.bias = dec_b1; p.bnsc = bn2sc; p.bnsh = bn2sh;
  p.dhi = aHh; p.dlo = nullptr; p.dstride = 2048;
  gemm_k<0, 3, false><<<dim3(64, 16), 256, 0, stream>>>(
      aZh, aZl, 256, wDec1H, wDec1L, 256, 2048, p);

  // ---- attn L1 merged [256², M=16384, NM=1] ----
  p = EpParams{};
  p.bias = bias_o1; p.bias2 = bias_l1; p.b2 = wL1H;
  p.dhi = aTh; p.dstride = 1024;
  gemm256_k<2, 1, false><<<dim3(64, 4), 512, 0, stream>>>(
      aOLh, nullptr, 1024, wO1H, 1024, 1024, p);

  // ---- attn L2 merged [128², M=16384, NM=1] ----
  p = EpParams{};
  p.bias = bias_o2; p.bias2 = bias_l2; p.b2 = wL2H;
  p.f32a = logitsO; p.f32b = logitsL;
  gemm_k<5, 1, false><<<dim3(128, 1), 256, 0, stream>>>(
      aTh, nullptr, 1024, wO2H, nullptr, 1024, 128, p);

  softmax_combine<<<32, 256, 0, stream>>>(logitsO, logitsL, nsc, esc);

  // ---- decode2 + fused attention scaling [256², NM=1] ----
  p = EpParams{};
  p.bias = dec_b2; p.nscale = nsc; p.escale = esc;
  p.f32a = out_edge; p.f32b = out_node;
  gemm256_k<4, 1, false><<<dim3(32, 12), 512, 0, stream>>>(
      aHh, nullptr, 2048, wDec2H, 2048, 2820, p);
}

// Round 5
// 876.210 us; speedup vs baseline: 1.0043x; 1.0043x over previous
//
#include <hip/hip_runtime.h>

using u16 = unsigned short;
using u32 = unsigned int;

typedef __attribute__((ext_vector_type(8))) short bf16x8;
typedef __attribute__((ext_vector_type(4))) float f32x4;

#define MFMA16 __builtin_amdgcn_mfma_f32_16x16x32_bf16

// ---------- fp32 <-> bf16 hi/lo split helpers ----------
__device__ __forceinline__ u16 f2bf(float f) {
  u32 u = __float_as_uint(f);
  u += 0x7fffu + ((u >> 16) & 1u);   // RNE
  return (u16)(u >> 16);
}
__device__ __forceinline__ float bf2f(u16 h) { return __uint_as_float(((u32)h) << 16); }

// async global->LDS, 16B per lane; LDS dest is wave-uniform base + lane*16
__device__ __forceinline__ void gld16(const u16* g, u16* s) {
  __builtin_amdgcn_global_load_lds((const __attribute__((address_space(1))) u32*)g,
                                   (__attribute__((address_space(3))) u32*)s, 16, 0, 0);
}

struct EpParams {
  const float* bias;
  const float* bias2;      // second-half bias (merged attn)
  const u16* b2;           // second-half B (merged attn)
  const float* bnsc;
  const float* bnsh;
  u16* dhi; u16* dlo; int dstride;
  float* f32a; float* f32b; int f32stride;
  const float* nscale; const float* escale;
};

// ---------------------------------------------------------------------------
// 256x256 8-wave pipelined GEMM (T3+T4+T5), BK=32, TRIPLE-buffered LDS.
// Race-free by construction: staging targets slot (t+2)%3, readers use t%3;
// end-of-iter lgkmcnt(0) + counted vmcnt + barrier close the only hazards.
// LDS is fragment-ordered (lane-linear DMA writes AND ds_read_b128) => zero
// bank conflicts [R4-verified: SQ_LDS_BANK_CONFLICT == 0].
// R5: sched_barrier(0) REMOVED (m141 regression reproduced in R4: 489 TF).
// Compiler-visible ds_reads keep dep-order; asm "memory" waits keep the
// slot-release/staging-arrival ordering => correctness unchanged.
// EP: 0 = bias->ReLU->BN (hi[+lo])  2 = tanh (B/bias by tm-half)  4 = dec2
// ---------------------------------------------------------------------------
template<int EP, int NM, bool SLO>
__global__ __launch_bounds__(512, 2) void gemm256_k(
    const u16* __restrict__ Ah, const u16* __restrict__ Al, int lda,
    const u16* __restrict__ Bh, int K, int N, EpParams p)
{
  __shared__ __align__(16) u16 sA[3][8192];
  __shared__ __align__(16) u16 sB[3][8192];
  __shared__ __align__(16) u16 sAl[(NM >= 2) ? 3 : 1][8192];

  const int t = threadIdx.x;
  const int lane = t & 63, wid = t >> 6;
  const int wm = wid >> 2, wn = wid & 3;
  const int fr = lane & 15, fg = lane >> 4;
  const int tm = blockIdx.x, tn = blockIdx.y;
  const int NT = K >> 5;

  const u16* BhS = Bh;
  const float* bias = p.bias;
  if constexpr (EP == 2) {
    if (tm >= 32) { BhS = p.b2; bias = p.bias2; }
  }

  const int strow = wid * 16 + fr;
  const u16* gA  = Ah + (size_t)(tm * 256 + strow) * (size_t)lda + fg * 8;
  const u16* gAl = (NM >= 2) ? Al + (size_t)(tm * 256 + strow) * (size_t)lda + fg * 8 : gA;
  const u16* gB  = BhS + (size_t)(tn * 256 + strow) * (size_t)K + fg * 8;

  auto stA = [&](int slot, int c, int k0) {
    gld16(gA + (size_t)c * 128 * lda + k0, &sA[slot][c * 4096 + wid * 512]);
  };
  auto stL = [&](int slot, int c, int k0) {
    gld16(gAl + (size_t)c * 128 * lda + k0, &sAl[slot][c * 4096 + wid * 512]);
  };
  auto stB = [&](int slot, int c, int k0) {
    gld16(gB + (size_t)c * 128 * K + k0, &sB[slot][c * 4096 + wid * 512]);
  };

  f32x4 acc[8][4];
#pragma unroll
  for (int m = 0; m < 8; m++)
#pragma unroll
    for (int n = 0; n < 4; n++) acc[m][n] = f32x4{0.f, 0.f, 0.f, 0.f};

  // ---- prologue: stage K-tiles 0 and 1 ----
  stA(0, 0, 0); stA(0, 1, 0);
  if constexpr (NM >= 2) { stL(0, 0, 0); stL(0, 1, 0); }
  stB(0, 0, 0); stB(0, 1, 0);
  stA(1, 0, 32); stA(1, 1, 32);
  if constexpr (NM >= 2) { stL(1, 0, 32); stL(1, 1, 32); }
  stB(1, 0, 32); stB(1, 1, 32);
  if constexpr (NM >= 2) asm volatile("s_waitcnt vmcnt(6)" ::: "memory");
  else                   asm volatile("s_waitcnt vmcnt(4)" ::: "memory");
  __builtin_amdgcn_s_barrier();

  for (int tt = 0; tt < NT; ++tt) {
    const int slot = tt % 3;
    const int nsl  = (tt + 2) % 3;
    const int k2   = (tt + 2) << 5;
    const bool SG  = (tt + 2 < NT);
    const u16* sa  = sA[slot];
    const u16* sb  = sB[slot];
    const u16* sal = sAl[(NM >= 2) ? slot : 0];

    bf16x8 bfr[4], ah[4], al[4];
    // -------- phase 0: m = 0..3 --------
#pragma unroll
    for (int n = 0; n < 4; ++n) bfr[n] = *(const bf16x8*)&sb[(wn * 4 + n) * 512 + lane * 8];
#pragma unroll
    for (int m = 0; m < 4; ++m) ah[m] = *(const bf16x8*)&sa[(wm * 8 + m) * 512 + lane * 8];
    if constexpr (NM >= 2) {
#pragma unroll
      for (int m = 0; m < 4; ++m) al[m] = *(const bf16x8*)&sal[(wm * 8 + m) * 512 + lane * 8];
    }
    if (SG) {
      stA(nsl, 0, k2); stA(nsl, 1, k2);
      if constexpr (NM >= 2) stL(nsl, 0, k2);
    }
    __builtin_amdgcn_s_barrier();
    __builtin_amdgcn_s_setprio(1);
#pragma unroll
    for (int m = 0; m < 4; ++m)
#pragma unroll
      for (int n = 0; n < 4; ++n) {
        if constexpr (NM >= 2) acc[m][n] = MFMA16(al[m], bfr[n], acc[m][n], 0, 0, 0);
        acc[m][n] = MFMA16(ah[m], bfr[n], acc[m][n], 0, 0, 0);
      }
    __builtin_amdgcn_s_setprio(0);
    __builtin_amdgcn_s_barrier();
    // -------- phase 1: m = 4..7 --------
#pragma unroll
    for (int m = 0; m < 4; ++m) ah[m] = *(const bf16x8*)&sa[(wm * 8 + 4 + m) * 512 + lane * 8];
    if constexpr (NM >= 2) {
#pragma unroll
      for (int m = 0; m < 4; ++m) al[m] = *(const bf16x8*)&sal[(wm * 8 + 4 + m) * 512 + lane * 8];
    }
    if (SG) {
      if constexpr (NM >= 2) stL(nsl, 1, k2);
      stB(nsl, 0, k2); stB(nsl, 1, k2);
    }
    __builtin_amdgcn_s_barrier();
    __builtin_amdgcn_s_setprio(1);
#pragma unroll
    for (int m = 0; m < 4; ++m)
#pragma unroll
      for (int n = 0; n < 4; ++n) {
        if constexpr (NM >= 2) acc[4 + m][n] = MFMA16(al[m], bfr[n], acc[4 + m][n], 0, 0, 0);
        acc[4 + m][n] = MFMA16(ah[m], bfr[n], acc[4 + m][n], 0, 0, 0);
      }
    __builtin_amdgcn_s_setprio(0);
    asm volatile("s_waitcnt lgkmcnt(0)" ::: "memory");
    if (SG) {
      if constexpr (NM >= 2) asm volatile("s_waitcnt vmcnt(6)" ::: "memory");
      else                   asm volatile("s_waitcnt vmcnt(4)" ::: "memory");
    } else {
      asm volatile("s_waitcnt vmcnt(0)" ::: "memory");
    }
    __builtin_amdgcn_s_barrier();
  }

  // ---- epilogue: C/D layout col=lane&15, row=4*(lane>>4)+reg [m89] ----
  const int rowb = tm * 256 + wm * 128;
  const int colb = tn * 256 + wn * 64;
#pragma unroll
  for (int n = 0; n < 4; ++n) {
    const int col = colb + n * 16 + fr;
#pragma unroll
    for (int m = 0; m < 8; ++m) {
#pragma unroll
      for (int r = 0; r < 4; ++r) {
        const int row = rowb + m * 16 + fg * 4 + r;
        float val = acc[m][n][r];
        if constexpr (EP == 0) {
          val += bias[col];
          val = fmaxf(val, 0.f);
          val = val * p.bnsc[col] + p.bnsh[col];
          u16 h = f2bf(val);
          p.dhi[(size_t)row * p.dstride + col] = h;
          if constexpr (SLO)
            p.dlo[(size_t)row * p.dstride + col] = f2bf(val - bf2f(h));
        } else if constexpr (EP == 2) {
          val = tanhf(val + bias[col]);
          p.dhi[(size_t)row * p.dstride + col] = f2bf(val);
        } else {                         // EP==4: dec2 -> scaled edge/node out
          if (col < N) {
            val += bias[col];
            if (col < 900) {
              int rr = col / 30, cc = col - rr * 30;
              float s = 1.f;
              if (rr >= 20 && cc >= 20 && rr <= cc) {
                int i0 = rr - 20, j0 = cc - 20;
                int k = i0 * 10 - ((i0 * (i0 - 1)) >> 1) + (j0 - i0);
                s = p.escale[(size_t)row * 55 + k];
              }
              p.f32a[(size_t)row * 900 + col] = val * s;
            } else {
              int tc = col - 900, rr = tc >> 6;
              float s = (rr >= 20) ? p.nscale[(size_t)row * 10 + (rr - 20)] : 1.f;
              p.f32b[(size_t)row * 1920 + tc] = val * s;
            }
          }
        }
      }
    }
  }
}

// ---------------------------------------------------------------------------
// 128x128 m97-structure GEMM (small/odd shapes).
// NM: 1 = A_h*B_h ; 2 = + A_l*B_h ; 3 = + A_h*B_l
// EP: 0=BN(ReLU)(+SLO)  1=mu/lv  5=merged attn L2 logits
// ---------------------------------------------------------------------------
template<int EP, int NM, bool SLO>
__global__ __launch_bounds__(256, (NM == 1) ? 3 : 2) void gemm_k(
    const u16* __restrict__ Ah, const u16* __restrict__ Al, int lda,
    const u16* __restrict__ Bh, const u16* __restrict__ Bl,
    int K, int N, EpParams p)
{
  __shared__ __align__(16) u16 sAh[4096], sBh[4096];
  __shared__ __align__(16) u16 sAl[(NM >= 2) ? 4096 : 16];
  __shared__ __align__(16) u16 sBl[(NM == 3) ? 4096 : 16];
  const int t = threadIdx.x;
  const int lane = t & 63, wid = t >> 6;
  const int tm = blockIdx.x, tn = blockIdx.y;

  const u16* BhS = Bh;
  if constexpr (EP == 5) { if (tm >= 64) BhS = p.b2; }

  const int rp = t >> 2, sp = t & 3;
  const int rl = (rp & ~1) | ((rp & 1) ^ ((rp >> 2) & 1));
  const int sl = sp ^ (rl & 3);
  const u16* pAh = Ah + (size_t)(tm * 128 + rl) * (size_t)lda + sl * 8;
  const u16* pBh = BhS + (size_t)(tn * 128 + rl) * (size_t)K + sl * 8;
  const u16* pAl = (NM >= 2) ? Al + (size_t)(tm * 128 + rl) * (size_t)lda + sl * 8 : pAh;
  const u16* pBl = (NM == 3) ? Bl + (size_t)(tn * 128 + rl) * (size_t)K + sl * 8 : pBh;
  const size_t aStep = (size_t)64 * (size_t)lda;
  const size_t bStep = (size_t)64 * (size_t)K;

  f32x4 acc[4][4];
#pragma unroll
  for (int m = 0; m < 4; m++)
#pragma unroll
    for (int n = 0; n < 4; n++) acc[m][n] = f32x4{0.f, 0.f, 0.f, 0.f};

  const int fr = lane & 15, fg = lane >> 4;
  const int wm = wid >> 1, wn = wid & 1;

  for (int kk = 0; kk < K; kk += 32) {
    gld16(pAh + kk,          sAh + wid * 512);
    gld16(pAh + aStep + kk,  sAh + 2048 + wid * 512);
    gld16(pBh + kk,          sBh + wid * 512);
    gld16(pBh + bStep + kk,  sBh + 2048 + wid * 512);
    if constexpr (NM >= 2) {
      gld16(pAl + kk,         sAl + wid * 512);
      gld16(pAl + aStep + kk, sAl + 2048 + wid * 512);
    }
    if constexpr (NM == 3) {
      gld16(pBl + kk,         sBl + wid * 512);
      gld16(pBl + bStep + kk, sBl + 2048 + wid * 512);
    }
    __syncthreads();

    bf16x8 a_h[4], b_h[4], a_l[4], b_l[4];
#pragma unroll
    for (int f = 0; f < 4; f++) {
      const int ar = wm * 64 + f * 16 + fr;
      const int br = wn * 64 + f * 16 + fr;
      a_h[f] = *(const bf16x8*)&sAh[(ar * 32 + fg * 8) ^ ((ar & 7) << 3)];
      b_h[f] = *(const bf16x8*)&sBh[(br * 32 + fg * 8) ^ ((br & 7) << 3)];
      if constexpr (NM >= 2) a_l[f] = *(const bf16x8*)&sAl[(ar * 32 + fg * 8) ^ ((ar & 7) << 3)];
      if constexpr (NM == 3) b_l[f] = *(const bf16x8*)&sBl[(br * 32 + fg * 8) ^ ((br & 7) << 3)];
    }
#pragma unroll
    for (int m = 0; m < 4; m++)
#pragma unroll
      for (int n = 0; n < 4; n++) {
        if constexpr (NM == 3)
          acc[m][n] = MFMA16(a_h[m], b_l[n], acc[m][n], 0, 0, 0);
        if constexpr (NM >= 2)
          acc[m][n] = MFMA16(a_l[m], b_h[n], acc[m][n], 0, 0, 0);
        acc[m][n] = MFMA16(a_h[m], b_h[n], acc[m][n], 0, 0, 0);
      }
    __syncthreads();
  }

  const int rowb = tm * 128 + wm * 64;
  const int colb = tn * 128 + wn * 64;
#pragma unroll
  for (int n = 0; n < 4; n++) {
    const int col = colb + n * 16 + fr;
#pragma unroll
    for (int m = 0; m < 4; m++) {
#pragma unroll
      for (int r = 0; r < 4; r++) {
        const int row = rowb + m * 16 + fg * 4 + r;
        float val = acc[m][n][r];
        if constexpr (EP == 0) {
          val += p.bias[col];
          val = fmaxf(val, 0.f);
          val = val * p.bnsc[col] + p.bnsh[col];
          u16 h = f2bf(val);
          p.dhi[(size_t)row * p.dstride + col] = h;
          if constexpr (SLO)
            p.dlo[(size_t)row * p.dstride + col] = f2bf(val - bf2f(h));
        } else if constexpr (EP == 1) {
          val += p.bias[col];
          if (col < 256) {
            p.f32a[(size_t)row * 256 + col] = val;
            u16 h = f2bf(val);
            p.dhi[(size_t)row * 256 + col] = h;
            p.dlo[(size_t)row * 256 + col] = f2bf(val - bf2f(h));
          } else {
            p.f32b[(size_t)row * 256 + (col - 256)] = val;
          }
        } else if constexpr (EP == 5) {  // merged attn L2 logits
          if (tm < 64) {
            if (col < 65) p.f32a[(size_t)row * 65 + col] = val + p.bias[col];
          } else {
            if (col < 90) p.f32b[(size_t)(row - 8192) * 90 + col] = val + p.bias2[col];
          }
        }
      }
    }
  }
}

// ---------- fused input conversion: x -> hi/lo ; optical,log -> hi only ----------
__global__ void conv3(const float* __restrict__ x, const float* __restrict__ opt,
                      const float* __restrict__ lg, u16* __restrict__ xh,
                      u16* __restrict__ xl, u16* __restrict__ oh, u16* __restrict__ lh) {
  const int SEG = 8192 * 1024 / 4;
  int i = blockIdx.x * blockDim.x + threadIdx.x;
  if (i < SEG) {
    float4 v = ((const float4*)x)[i];
    ushort4 hh, ll;
    hh.x = f2bf(v.x); ll.x = f2bf(v.x - bf2f(hh.x));
    hh.y = f2bf(v.y); ll.y = f2bf(v.y - bf2f(hh.y));
    hh.z = f2bf(v.z); ll.z = f2bf(v.z - bf2f(hh.z));
    hh.w = f2bf(v.w); ll.w = f2bf(v.w - bf2f(hh.w));
    ((ushort4*)xh)[i] = hh;
    ((ushort4*)xl)[i] = ll;
  } else if (i < 2 * SEG) {
    int j = i - SEG;
    float4 v = ((const float4*)opt)[j];
    ushort4 hh;
    hh.x = f2bf(v.x); hh.y = f2bf(v.y); hh.z = f2bf(v.z); hh.w = f2bf(v.w);
    ((ushort4*)oh)[j] = hh;
  } else if (i < 3 * SEG) {
    int j = i - 2 * SEG;
    float4 v = ((const float4*)lg)[j];
    ushort4 hh;
    hh.x = f2bf(v.x); hh.y = f2bf(v.y); hh.z = f2bf(v.z); hh.w = f2bf(v.w);
    ((ushort4*)lh)[j] = hh;
  }
}

// ---------- W[K,N] fp32 -> Wt hi(/lo) [.,K] transposed, zero-pad n>=N ----------
__global__ void conv_wT(const float* __restrict__ W, u16* __restrict__ Th,
                        u16* __restrict__ Tl, int K, int N) {
  __shared__ float tile[32][33];
  int k0 = blockIdx.x * 32, n0 = blockIdx.y * 32;
  int tx = threadIdx.x, ty = threadIdx.y;
#pragma unroll
  for (int i = ty; i < 32; i += 8) {
    int n = n0 + tx;
    tile[i][tx] = (n < N) ? W[(size_t)(k0 + i) * N + n] : 0.f;
  }
  __syncthreads();
#pragma unroll
  for (int i = ty; i < 32; i += 8) {
    int n = n0 + i, k = k0 + tx;
    float v = tile[tx][i];
    u16 h = f2bf(v);
    Th[(size_t)n * K + k] = h;
    if (Tl) Tl[(size_t)n * K + k] = f2bf(v - bf2f(h));
  }
}

// ---------- block-diag [Wa(512xNa); Wb(512xNb)] -> Wt [128,1024] hi ----------
__global__ void conv_w2bd(const float* __restrict__ Wa, int Na,
                          const float* __restrict__ Wb, int Nb,
                          u16* __restrict__ Th) {
  int idx = blockIdx.x * blockDim.x + threadIdx.x;
  if (idx >= 128 * 1024) return;
  int n = idx >> 10, k = idx & 1023;
  float v = 0.f;
  if (n < Na) { if (k < 512) v = Wa[(size_t)k * Na + n]; }
  else if (n < Na + Nb) { if (k >= 512) v = Wb[(size_t)(k - 512) * Nb + (n - Na)]; }
  Th[idx] = f2bf(v);
}

// ---------- single prep kernel: BN folds + all bias concats ----------
struct PrepArgs {
  const float *bn1_g, *bn1_b, *bn1_m, *bn1_v, *bn2_g, *bn2_b, *bn2_m, *bn2_v;
  const float *mu_b, *lv_b, *on_b1, *oe_b1, *ln_b1, *le_b1, *on_b2, *oe_b2, *ln_b2, *le_b2;
  float *bn1sc, *bn1sh, *bn2sc, *bn2sh, *bias_mulv, *bias_o1, *bias_l1, *bias_o2, *bias_l2;
};
__global__ void prep_k(PrepArgs a) {
  int i = blockIdx.x * blockDim.x + threadIdx.x;
  if (i < 2048) {
    float s = a.bn1_g[i] * rsqrtf(a.bn1_v[i] + 1e-5f);
    a.bn1sc[i] = s; a.bn1sh[i] = a.bn1_b[i] - a.bn1_m[i] * s;
  } else if (i < 4096) {
    int j = i - 2048;
    float s = a.bn2_g[j] * rsqrtf(a.bn2_v[j] + 1e-5f);
    a.bn2sc[j] = s; a.bn2sh[j] = a.bn2_b[j] - a.bn2_m[j] * s;
  } else if (i < 4608) {
    int j = i - 4096; a.bias_mulv[j] = (j < 256) ? a.mu_b[j] : a.lv_b[j - 256];
  } else if (i < 5632) {
    int j = i - 4608; a.bias_o1[j] = (j < 512) ? a.on_b1[j] : a.oe_b1[j - 512];
  } else if (i < 6656) {
    int j = i - 5632; a.bias_l1[j] = (j < 512) ? a.ln_b1[j] : a.le_b1[j - 512];
  } else if (i < 6721) {
    int j = i - 6656; a.bias_o2[j] = (j < 10) ? a.on_b2[j] : a.oe_b2[j - 10];
  } else if (i < 6811) {
    int j = i - 6721; a.bias_l2[j] = (j < 12) ? a.ln_b2[j] : a.le_b2[j - 12];
  }
}

// ---------- combined double softmax -> per-batch scales ----------
__global__ void softmax_combine(const float* __restrict__ lo, const float* __restrict__ ll,
                                float* __restrict__ nsc, float* __restrict__ esc) {
  int b = blockIdx.x * blockDim.x + threadIdx.x;
  if (b >= 8192) return;
  const float* po = lo + (size_t)b * 65;
  const float* pl = ll + (size_t)b * 90;
  float mo = po[0];
  for (int i = 1; i < 10; i++) mo = fmaxf(mo, po[i]);
  float so = 0.f;
  for (int i = 0; i < 10; i++) so += expf(po[i] - mo);
  float ml = pl[0];
  for (int i = 1; i < 12; i++) ml = fmaxf(ml, pl[i]);
  float sl = 0.f;
  for (int i = 0; i < 12; i++) sl += expf(pl[i] - ml);
  float invn = 1.f / (so * sl);
  for (int i = 0; i < 10; i++)
    nsc[(size_t)b * 10 + i] = expf(po[i] - mo) * expf(pl[i] - ml) * invn;
  const float* qo = po + 10;
  const float* ql = pl + 12;
  float meo = qo[0];
  for (int i = 1; i < 55; i++) meo = fmaxf(meo, qo[i]);
  float seo = 0.f;
  for (int i = 0; i < 55; i++) seo += expf(qo[i] - meo);
  float mel = ql[0];
  for (int i = 1; i < 78; i++) mel = fmaxf(mel, ql[i]);
  float sel = 0.f;
  for (int i = 0; i < 78; i++) sel += expf(ql[i] - mel);
  float inve = 1.f / (seo * sel);
  for (int k = 0; k < 55; k++)
    esc[(size_t)b * 55 + k] = expf(qo[k] - meo) * expf(ql[k] - mel) * inve;
}

// ---------------------------------------------------------------------------
extern "C" void kernel_launch(void* const* d_in, const int* in_sizes, int n_in,
                              void* d_out, int out_size, void* d_ws, size_t ws_size,
                              hipStream_t stream) {
  const float* x       = (const float*)d_in[0];
  const float* optical = (const float*)d_in[1];
  const float* logx    = (const float*)d_in[2];
  const float* enc_W   = (const float*)d_in[3];
  const float* enc_b   = (const float*)d_in[4];
  const float* bn1_g   = (const float*)d_in[5];
  const float* bn1_b   = (const float*)d_in[6];
  const float* bn1_m   = (const float*)d_in[7];
  const float* bn1_v   = (const float*)d_in[8];
  const float* mu_W    = (const float*)d_in[9];
  const float* mu_b    = (const float*)d_in[10];
  const float* lv_W    = (const float*)d_in[11];
  const float* lv_b    = (const float*)d_in[12];
  const float* dec_W1  = (const float*)d_in[13];
  const float* dec_b1  = (const float*)d_in[14];
  const float* bn2_g   = (const float*)d_in[15];
  const float* bn2_b   = (const float*)d_in[16];
  const float* bn2_m   = (const float*)d_in[17];
  const float* bn2_v   = (const float*)d_in[18];
  const float* dec_W2  = (const float*)d_in[19];
  const float* dec_b2  = (const float*)d_in[20];
  const float* on_W1   = (const float*)d_in[21];
  const float* on_b1   = (const float*)d_in[22];
  const float* on_W2   = (const float*)d_in[23];
  const float* on_b2   = (const float*)d_in[24];
  const float* oe_W1   = (const float*)d_in[25];
  const float* oe_b1   = (const float*)d_in[26];
  const float* oe_W2   = (const float*)d_in[27];
  const float* oe_b2   = (const float*)d_in[28];
  const float* ln_W1   = (const float*)d_in[29];
  const float* ln_b1   = (const float*)d_in[30];
  const float* ln_W2   = (const float*)d_in[31];
  const float* ln_b2   = (const float*)d_in[32];
  const float* le_W1   = (const float*)d_in[33];
  const float* le_b1   = (const float*)d_in[34];
  const float* le_W2   = (const float*)d_in[35];
  const float* le_b2   = (const float*)d_in[36];

  const int B = 8192;
  float* out_edge = (float*)d_out;
  float* out_node = out_edge + (size_t)B * 900;
  float* out_mu   = out_node + (size_t)B * 1920;
  float* out_lv   = out_mu + (size_t)B * 256;

  // ---- workspace carve ----
  char* base = (char*)d_ws;
  size_t off = 0;
  auto takeB = [&](size_t elems) -> u16* {
    u16* p = (u16*)(base + off);
    off = (off + elems * 2 + 255) & ~(size_t)255;
    return p;
  };
  auto takeF = [&](size_t elems) -> float* {
    float* p = (float*)(base + off);
    off = (off + elems * 4 + 255) & ~(size_t)255;
    return p;
  };
  u16* wEncH  = takeB(2048 * 1024);
  u16* wMulvH = takeB(512 * 2048);   u16* wMulvL = takeB(512 * 2048);
  u16* wDec1H = takeB(2048 * 256);   u16* wDec1L = takeB(2048 * 256);
  u16* wDec2H = takeB(3072 * 2048);                 // padded to 3072 rows
  u16* wO1H   = takeB(1024 * 1024);
  u16* wL1H   = takeB(1024 * 1024);
  u16* wO2H   = takeB(128 * 1024);
  u16* wL2H   = takeB(128 * 1024);
  u16* aXh = takeB((size_t)B * 1024); u16* aXl = takeB((size_t)B * 1024);
  u16* aOLh = takeB((size_t)2 * B * 1024);          // [16384,1024]: opt | log
  u16* aOh = aOLh;
  u16* aLh = aOLh + (size_t)B * 1024;
  u16* aHh = takeB((size_t)B * 2048); u16* aHl = takeB((size_t)B * 2048);
  u16* aZh = takeB((size_t)B * 256);  u16* aZl = takeB((size_t)B * 256);
  u16* aTh = takeB((size_t)2 * B * 1024);           // [16384,1024] tanh out
  float* logitsO = takeF((size_t)B * 65);
  float* logitsL = takeF((size_t)B * 90);
  float* nsc = takeF((size_t)B * 10);
  float* esc = takeF((size_t)B * 55);
  float* bn1sc = takeF(2048); float* bn1sh = takeF(2048);
  float* bn2sc = takeF(2048); float* bn2sh = takeF(2048);
  float* bias_mulv = takeF(512);
  float* bias_o1 = takeF(1024);
  float* bias_l1 = takeF(1024);
  float* bias_o2 = takeF(65);
  float* bias_l2 = takeF(90);

  // ---- prep ----
  PrepArgs pa;
  pa.bn1_g = bn1_g; pa.bn1_b = bn1_b; pa.bn1_m = bn1_m; pa.bn1_v = bn1_v;
  pa.bn2_g = bn2_g; pa.bn2_b = bn2_b; pa.bn2_m = bn2_m; pa.bn2_v = bn2_v;
  pa.mu_b = mu_b; pa.lv_b = lv_b;
  pa.on_b1 = on_b1; pa.oe_b1 = oe_b1; pa.ln_b1 = ln_b1; pa.le_b1 = le_b1;
  pa.on_b2 = on_b2; pa.oe_b2 = oe_b2; pa.ln_b2 = ln_b2; pa.le_b2 = le_b2;
  pa.bn1sc = bn1sc; pa.bn1sh = bn1sh; pa.bn2sc = bn2sc; pa.bn2sh = bn2sh;
  pa.bias_mulv = bias_mulv; pa.bias_o1 = bias_o1; pa.bias_l1 = bias_l1;
  pa.bias_o2 = bias_o2; pa.bias_l2 = bias_l2;
  prep_k<<<27, 256, 0, stream>>>(pa);

  conv3<<<24576, 256, 0, stream>>>(x, optical, logx, aXh, aXl, aOh, aLh);

  dim3 tb(32, 8);
  conv_wT<<<dim3(32, 64), tb, 0, stream>>>(enc_W, wEncH, nullptr, 1024, 2048);
  conv_wT<<<dim3(64, 8), tb, 0, stream>>>(mu_W, wMulvH, wMulvL, 2048, 256);
  conv_wT<<<dim3(64, 8), tb, 0, stream>>>(
      lv_W, wMulvH + (size_t)256 * 2048, wMulvL + (size_t)256 * 2048, 2048, 256);
  conv_wT<<<dim3(8, 64), tb, 0, stream>>>(dec_W1, wDec1H, wDec1L, 256, 2048);
  conv_wT<<<dim3(64, 96), tb, 0, stream>>>(dec_W2, wDec2H, nullptr, 2048, 2820);
  conv_wT<<<dim3(32, 16), tb, 0, stream>>>(on_W1, wO1H, nullptr, 1024, 512);
  conv_wT<<<dim3(32, 16), tb, 0, stream>>>(oe_W1, wO1H + (size_t)512 * 1024, nullptr, 1024, 512);
  conv_wT<<<dim3(32, 16), tb, 0, stream>>>(ln_W1, wL1H, nullptr, 1024, 512);
  conv_wT<<<dim3(32, 16), tb, 0, stream>>>(le_W1, wL1H + (size_t)512 * 1024, nullptr, 1024, 512);
  conv_w2bd<<<512, 256, 0, stream>>>(on_W2, 10, oe_W2, 55, wO2H);
  conv_w2bd<<<512, 256, 0, stream>>>(ln_W2, 12, le_W2, 78, wL2H);

  EpParams p;

  // ---- encode [256² pipeline, NM=2] ----
  p = EpParams{};
  p.bias = enc_b; p.bnsc = bn1sc; p.bnsh = bn1sh;
  p.dhi = aHh; p.dlo = aHl; p.dstride = 2048;
  gemm256_k<0, 2, true><<<dim3(32, 8), 512, 0, stream>>>(
      aXh, aXl, 1024, wEncH, 1024, 2048, p);

  // ---- mu | logvar [128², NM=3] ----
  p = EpParams{};
  p.bias = bias_mulv; p.f32a = out_mu; p.f32b = out_lv;
  p.dhi = aZh; p.dlo = aZl; p.dstride = 256;
  gemm_k<1, 3, false><<<dim3(64, 4), 256, 0, stream>>>(
      aHh, aHl, 2048, wMulvH, wMulvL, 2048, 512, p);

  // ---- decode1 [128², NM=3, hi-only] ----
  p = EpParams{};
  p.bias = dec_b1; p.bnsc = bn2sc; p.bnsh = bn2sh;
  p.dhi = aHh; p.dlo = nullptr; p.dstride = 2048;
  gemm_k<0, 3, false><<<dim3(64, 16), 256, 0, stream>>>(
      aZh, aZl, 256, wDec1H, wDec1L, 256, 2048, p);

  // ---- attn L1 merged [256², M=16384, NM=1] ----
  p = EpParams{};
  p.bias = bias_o1; p.bias2 = bias_l1; p.b2 = wL1H;
  p.dhi = aTh; p.dstride = 1024;
  gemm256_k<2, 1, false><<<dim3(64, 4), 512, 0, stream>>>(
      aOLh, nullptr, 1024, wO1H, 1024, 1024, p);

  // ---- attn L2 merged [128², M=16384, NM=1] ----
  p = EpParams{};
  p.bias = bias_o2; p.bias2 = bias_l2; p.b2 = wL2H;
  p.f32a = logitsO; p.f32b = logitsL;
  gemm_k<5, 1, false><<<dim3(128, 1), 256, 0, stream>>>(
      aTh, nullptr, 1024, wO2H, nullptr, 1024, 128, p);

  softmax_combine<<<32, 256, 0, stream>>>(logitsO, logitsL, nsc, esc);

  // ---- decode2 + fused attention scaling [256², NM=1] ----
  p = EpParams{};
  p.bias = dec_b2; p.nscale = nsc; p.escale = esc;
  p.f32a = out_edge; p.f32b = out_node;
  gemm256_k<4, 1, false><<<dim3(32, 12), 512, 0, stream>>>(
      aHh, nullptr, 2048, wDec2H, 2048, 2820, p);
}

// Round 6
// 786.026 us; speedup vs baseline: 1.1196x; 1.1147x over previous
//
#include <hip/hip_runtime.h>

using u16 = unsigned short;
using u32 = unsigned int;

typedef __attribute__((ext_vector_type(8))) short bf16x8;
typedef __attribute__((ext_vector_type(4))) float f32x4;

#define MFMA16 __builtin_amdgcn_mfma_f32_16x16x32_bf16

// ---------- fp32 <-> bf16 hi/lo split helpers ----------
__device__ __forceinline__ u16 f2bf(float f) {
  u32 u = __float_as_uint(f);
  u += 0x7fffu + ((u >> 16) & 1u);   // RNE
  return (u16)(u >> 16);
}
__device__ __forceinline__ float bf2f(u16 h) { return __uint_as_float(((u32)h) << 16); }

// async global->LDS, 16B per lane; LDS dest is wave-uniform base + lane*16
__device__ __forceinline__ void gld16(const u16* g, u16* s) {
  __builtin_amdgcn_global_load_lds((const __attribute__((address_space(1))) u32*)g,
                                   (__attribute__((address_space(3))) u32*)s, 16, 0, 0);
}

struct EpParams {
  const float* bias;
  const float* bias2;      // second-half bias (merged attn)
  const u16* b2;           // second-half B (merged attn)
  const float* bnsc;
  const float* bnsh;
  u16* dhi; u16* dlo; int dstride;
  float* f32a; float* f32b; int f32stride;
  const float* nscale; const float* escale;
};

// ---------------------------------------------------------------------------
// 128x128 m97-structure GEMM (R3-proven: 862us pipeline config).
// A row-major [M,K] hi(/lo); B TRANSPOSED [Npad,K] hi(/lo), zero-padded.
// BK=32, 4 waves (2x2), each wave 64x64 = 4x4 frags of 16x16.
// NM: 1 = A_h*B_h ; 2 = + A_l*B_h ; 3 = + A_h*B_l
// EP: 0=BN(ReLU)(+SLO hilo)  1=mu/lv  2=tanh merged (B/bias by tm-half)
//     4=dec2+fused attn scaling  5=merged attn L2 logits
// ---------------------------------------------------------------------------
template<int EP, int NM, bool SLO>
__global__ __launch_bounds__(256, (NM == 1) ? 3 : 2) void gemm_k(
    const u16* __restrict__ Ah, const u16* __restrict__ Al, int lda,
    const u16* __restrict__ Bh, const u16* __restrict__ Bl,
    int K, int N, EpParams p)
{
  __shared__ __align__(16) u16 sAh[4096], sBh[4096];
  __shared__ __align__(16) u16 sAl[(NM >= 2) ? 4096 : 16];
  __shared__ __align__(16) u16 sBl[(NM == 3) ? 4096 : 16];
  const int t = threadIdx.x;
  const int lane = t & 63, wid = t >> 6;
  const int tm = blockIdx.x, tn = blockIdx.y;

  const u16* BhS = Bh;
  const float* bias = p.bias;
  if constexpr (EP == 2 || EP == 5) {
    if (tm >= 64) { BhS = p.b2; bias = p.bias2; }
  }

  const int rp = t >> 2, sp = t & 3;
  const int rl = (rp & ~1) | ((rp & 1) ^ ((rp >> 2) & 1));
  const int sl = sp ^ (rl & 3);
  const u16* pAh = Ah + (size_t)(tm * 128 + rl) * (size_t)lda + sl * 8;
  const u16* pBh = BhS + (size_t)(tn * 128 + rl) * (size_t)K + sl * 8;
  const u16* pAl = (NM >= 2) ? Al + (size_t)(tm * 128 + rl) * (size_t)lda + sl * 8 : pAh;
  const u16* pBl = (NM == 3) ? Bl + (size_t)(tn * 128 + rl) * (size_t)K + sl * 8 : pBh;
  const size_t aStep = (size_t)64 * (size_t)lda;
  const size_t bStep = (size_t)64 * (size_t)K;

  f32x4 acc[4][4];
#pragma unroll
  for (int m = 0; m < 4; m++)
#pragma unroll
    for (int n = 0; n < 4; n++) acc[m][n] = f32x4{0.f, 0.f, 0.f, 0.f};

  const int fr = lane & 15, fg = lane >> 4;
  const int wm = wid >> 1, wn = wid & 1;

  for (int kk = 0; kk < K; kk += 32) {
    gld16(pAh + kk,          sAh + wid * 512);
    gld16(pAh + aStep + kk,  sAh + 2048 + wid * 512);
    gld16(pBh + kk,          sBh + wid * 512);
    gld16(pBh + bStep + kk,  sBh + 2048 + wid * 512);
    if constexpr (NM >= 2) {
      gld16(pAl + kk,         sAl + wid * 512);
      gld16(pAl + aStep + kk, sAl + 2048 + wid * 512);
    }
    if constexpr (NM == 3) {
      gld16(pBl + kk,         sBl + wid * 512);
      gld16(pBl + bStep + kk, sBl + 2048 + wid * 512);
    }
    __syncthreads();

    bf16x8 a_h[4], b_h[4], a_l[4], b_l[4];
#pragma unroll
    for (int f = 0; f < 4; f++) {
      const int ar = wm * 64 + f * 16 + fr;
      const int br = wn * 64 + f * 16 + fr;
      a_h[f] = *(const bf16x8*)&sAh[(ar * 32 + fg * 8) ^ ((ar & 7) << 3)];
      b_h[f] = *(const bf16x8*)&sBh[(br * 32 + fg * 8) ^ ((br & 7) << 3)];
      if constexpr (NM >= 2) a_l[f] = *(const bf16x8*)&sAl[(ar * 32 + fg * 8) ^ ((ar & 7) << 3)];
      if constexpr (NM == 3) b_l[f] = *(const bf16x8*)&sBl[(br * 32 + fg * 8) ^ ((br & 7) << 3)];
    }
#pragma unroll
    for (int m = 0; m < 4; m++)
#pragma unroll
      for (int n = 0; n < 4; n++) {
        if constexpr (NM == 3)
          acc[m][n] = MFMA16(a_h[m], b_l[n], acc[m][n], 0, 0, 0);
        if constexpr (NM >= 2)
          acc[m][n] = MFMA16(a_l[m], b_h[n], acc[m][n], 0, 0, 0);
        acc[m][n] = MFMA16(a_h[m], b_h[n], acc[m][n], 0, 0, 0);
      }
    __syncthreads();
  }

  // epilogue: C/D layout col=lane&15, row=4*(lane>>4)+reg [m89-verified]
  const int rowb = tm * 128 + wm * 64;
  const int colb = tn * 128 + wn * 64;
#pragma unroll
  for (int n = 0; n < 4; n++) {
    const int col = colb + n * 16 + fr;
#pragma unroll
    for (int m = 0; m < 4; m++) {
#pragma unroll
      for (int r = 0; r < 4; r++) {
        const int row = rowb + m * 16 + fg * 4 + r;
        float val = acc[m][n][r];
        if constexpr (EP == 0) {          // bias -> relu -> bn -> store
          val += bias[col];
          val = fmaxf(val, 0.f);
          val = val * p.bnsc[col] + p.bnsh[col];
          u16 h = f2bf(val);
          p.dhi[(size_t)row * p.dstride + col] = h;
          if constexpr (SLO)
            p.dlo[(size_t)row * p.dstride + col] = f2bf(val - bf2f(h));
        } else if constexpr (EP == 1) {   // mu (fp32 + hilo z) | logvar (fp32)
          val += bias[col];
          if (col < 256) {
            p.f32a[(size_t)row * 256 + col] = val;
            u16 h = f2bf(val);
            p.dhi[(size_t)row * 256 + col] = h;
            p.dlo[(size_t)row * 256 + col] = f2bf(val - bf2f(h));
          } else {
            p.f32b[(size_t)row * 256 + (col - 256)] = val;
          }
        } else if constexpr (EP == 2) {   // tanh -> bf16, merged halves
          val = tanhf(val + bias[col]);
          p.dhi[(size_t)row * p.dstride + col] = f2bf(val);
        } else if constexpr (EP == 5) {   // merged attn L2 logits
          if (tm < 64) {
            if (col < 65) p.f32a[(size_t)row * 65 + col] = val + bias[col];
          } else {
            if (col < 90) p.f32b[(size_t)(row - 8192) * 90 + col] = val + bias[col];
          }
        } else {                          // EP==4: dec2 -> scaled edge/node out
          if (col < N) {
            val += bias[col];
            if (col < 900) {
              int rr = col / 30, cc = col - rr * 30;
              float s = 1.f;
              if (rr >= 20 && cc >= 20 && rr <= cc) {
                int i0 = rr - 20, j0 = cc - 20;
                int k = i0 * 10 - ((i0 * (i0 - 1)) >> 1) + (j0 - i0);
                s = p.escale[(size_t)row * 55 + k];
              }
              p.f32a[(size_t)row * 900 + col] = val * s;
            } else {
              int tc = col - 900, rr = tc >> 6;
              float s = (rr >= 20) ? p.nscale[(size_t)row * 10 + (rr - 20)] : 1.f;
              p.f32b[(size_t)row * 1920 + tc] = val * s;
            }
          }
        }
      }
    }
  }
}

// ---------- fused input conversion: x -> hi/lo ; optical,log -> hi only ----------
__global__ void conv3(const float* __restrict__ x, const float* __restrict__ opt,
                      const float* __restrict__ lg, u16* __restrict__ xh,
                      u16* __restrict__ xl, u16* __restrict__ oh, u16* __restrict__ lh) {
  const int SEG = 8192 * 1024 / 4;
  int i = blockIdx.x * blockDim.x + threadIdx.x;
  if (i < SEG) {
    float4 v = ((const float4*)x)[i];
    ushort4 hh, ll;
    hh.x = f2bf(v.x); ll.x = f2bf(v.x - bf2f(hh.x));
    hh.y = f2bf(v.y); ll.y = f2bf(v.y - bf2f(hh.y));
    hh.z = f2bf(v.z); ll.z = f2bf(v.z - bf2f(hh.z));
    hh.w = f2bf(v.w); ll.w = f2bf(v.w - bf2f(hh.w));
    ((ushort4*)xh)[i] = hh;
    ((ushort4*)xl)[i] = ll;
  } else if (i < 2 * SEG) {
    int j = i - SEG;
    float4 v = ((const float4*)opt)[j];
    ushort4 hh;
    hh.x = f2bf(v.x); hh.y = f2bf(v.y); hh.z = f2bf(v.z); hh.w = f2bf(v.w);
    ((ushort4*)oh)[j] = hh;
  } else if (i < 3 * SEG) {
    int j = i - 2 * SEG;
    float4 v = ((const float4*)lg)[j];
    ushort4 hh;
    hh.x = f2bf(v.x); hh.y = f2bf(v.y); hh.z = f2bf(v.z); hh.w = f2bf(v.w);
    ((ushort4*)lh)[j] = hh;
  }
}

// ---------- ALL weight transposes fused: one launch, job table ----------
// W[K,N] fp32 -> Wt hi [Npad,K], zero-pad n>=N. Job picked by block range.
struct WTJob { const float* src; u16* dh; int K, N, nbx, blk0; };
struct WTJobs { WTJob j[9]; };
__global__ void conv_wT_all(WTJobs J) {
  __shared__ float tile[32][33];
  const int b = blockIdx.x;
  int ji = 0;
#pragma unroll
  for (int q = 1; q < 9; q++) if (b >= J.j[q].blk0) ji = q;
  const WTJob jb = J.j[ji];
  const int bl = b - jb.blk0;
  const int kb = bl % jb.nbx, nb = bl / jb.nbx;
  const int k0 = kb * 32, n0 = nb * 32;
  const int tx = threadIdx.x, ty = threadIdx.y;
#pragma unroll
  for (int i = ty; i < 32; i += 8) {
    int n = n0 + tx;
    tile[i][tx] = (n < jb.N) ? jb.src[(size_t)(k0 + i) * jb.N + n] : 0.f;
  }
  __syncthreads();
#pragma unroll
  for (int i = ty; i < 32; i += 8) {
    int n = n0 + i, k = k0 + tx;
    jb.dh[(size_t)n * jb.K + k] = f2bf(tile[tx][i]);
  }
}

// ---------- block-diag [Wa(512xNa); Wb(512xNb)] -> Wt [128,1024] hi ----------
__global__ void conv_w2bd(const float* __restrict__ Wa, int Na,
                          const float* __restrict__ Wb, int Nb,
                          u16* __restrict__ Th) {
  int idx = blockIdx.x * blockDim.x + threadIdx.x;
  if (idx >= 128 * 1024) return;
  int n = idx >> 10, k = idx & 1023;
  float v = 0.f;
  if (n < Na) { if (k < 512) v = Wa[(size_t)k * Na + n]; }
  else if (n < Na + Nb) { if (k >= 512) v = Wb[(size_t)(k - 512) * Nb + (n - Na)]; }
  Th[idx] = f2bf(v);
}

// ---------- single prep kernel: BN folds + all bias concats ----------
struct PrepArgs {
  const float *bn1_g, *bn1_b, *bn1_m, *bn1_v, *bn2_g, *bn2_b, *bn2_m, *bn2_v;
  const float *mu_b, *lv_b, *on_b1, *oe_b1, *ln_b1, *le_b1, *on_b2, *oe_b2, *ln_b2, *le_b2;
  float *bn1sc, *bn1sh, *bn2sc, *bn2sh, *bias_mulv, *bias_o1, *bias_l1, *bias_o2, *bias_l2;
};
__global__ void prep_k(PrepArgs a) {
  int i = blockIdx.x * blockDim.x + threadIdx.x;
  if (i < 2048) {
    float s = a.bn1_g[i] * rsqrtf(a.bn1_v[i] + 1e-5f);
    a.bn1sc[i] = s; a.bn1sh[i] = a.bn1_b[i] - a.bn1_m[i] * s;
  } else if (i < 4096) {
    int j = i - 2048;
    float s = a.bn2_g[j] * rsqrtf(a.bn2_v[j] + 1e-5f);
    a.bn2sc[j] = s; a.bn2sh[j] = a.bn2_b[j] - a.bn2_m[j] * s;
  } else if (i < 4608) {
    int j = i - 4096; a.bias_mulv[j] = (j < 256) ? a.mu_b[j] : a.lv_b[j - 256];
  } else if (i < 5632) {
    int j = i - 4608; a.bias_o1[j] = (j < 512) ? a.on_b1[j] : a.oe_b1[j - 512];
  } else if (i < 6656) {
    int j = i - 5632; a.bias_l1[j] = (j < 512) ? a.ln_b1[j] : a.le_b1[j - 512];
  } else if (i < 6721) {
    int j = i - 6656; a.bias_o2[j] = (j < 10) ? a.on_b2[j] : a.oe_b2[j - 10];
  } else if (i < 6811) {
    int j = i - 6721; a.bias_l2[j] = (j < 12) ? a.ln_b2[j] : a.le_b2[j - 12];
  }
}

// ---------- combined double softmax -> per-batch scales ----------
__global__ void softmax_combine(const float* __restrict__ lo, const float* __restrict__ ll,
                                float* __restrict__ nsc, float* __restrict__ esc) {
  int b = blockIdx.x * blockDim.x + threadIdx.x;
  if (b >= 8192) return;
  const float* po = lo + (size_t)b * 65;
  const float* pl = ll + (size_t)b * 90;
  float mo = po[0];
  for (int i = 1; i < 10; i++) mo = fmaxf(mo, po[i]);
  float so = 0.f;
  for (int i = 0; i < 10; i++) so += expf(po[i] - mo);
  float ml = pl[0];
  for (int i = 1; i < 12; i++) ml = fmaxf(ml, pl[i]);
  float sl = 0.f;
  for (int i = 0; i < 12; i++) sl += expf(pl[i] - ml);
  float invn = 1.f / (so * sl);
  for (int i = 0; i < 10; i++)
    nsc[(size_t)b * 10 + i] = expf(po[i] - mo) * expf(pl[i] - ml) * invn;
  const float* qo = po + 10;
  const float* ql = pl + 12;
  float meo = qo[0];
  for (int i = 1; i < 55; i++) meo = fmaxf(meo, qo[i]);
  float seo = 0.f;
  for (int i = 0; i < 55; i++) seo += expf(qo[i] - meo);
  float mel = ql[0];
  for (int i = 1; i < 78; i++) mel = fmaxf(mel, ql[i]);
  float sel = 0.f;
  for (int i = 0; i < 78; i++) sel += expf(ql[i] - mel);
  float inve = 1.f / (seo * sel);
  for (int k = 0; k < 55; k++)
    esc[(size_t)b * 55 + k] = expf(qo[k] - meo) * expf(ql[k] - mel) * inve;
}

// ---------------------------------------------------------------------------
extern "C" void kernel_launch(void* const* d_in, const int* in_sizes, int n_in,
                              void* d_out, int out_size, void* d_ws, size_t ws_size,
                              hipStream_t stream) {
  const float* x       = (const float*)d_in[0];
  const float* optical = (const float*)d_in[1];
  const float* logx    = (const float*)d_in[2];
  const float* enc_W   = (const float*)d_in[3];
  const float* enc_b   = (const float*)d_in[4];
  const float* bn1_g   = (const float*)d_in[5];
  const float* bn1_b   = (const float*)d_in[6];
  const float* bn1_m   = (const float*)d_in[7];
  const float* bn1_v   = (const float*)d_in[8];
  const float* mu_W    = (const float*)d_in[9];
  const float* mu_b    = (const float*)d_in[10];
  const float* lv_W    = (const float*)d_in[11];
  const float* lv_b    = (const float*)d_in[12];
  const float* dec_W1  = (const float*)d_in[13];
  const float* dec_b1  = (const float*)d_in[14];
  const float* bn2_g   = (const float*)d_in[15];
  const float* bn2_b   = (const float*)d_in[16];
  const float* bn2_m   = (const float*)d_in[17];
  const float* bn2_v   = (const float*)d_in[18];
  const float* dec_W2  = (const float*)d_in[19];
  const float* dec_b2  = (const float*)d_in[20];
  const float* on_W1   = (const float*)d_in[21];
  const float* on_b1   = (const float*)d_in[22];
  const float* on_W2   = (const float*)d_in[23];
  const float* on_b2   = (const float*)d_in[24];
  const float* oe_W1   = (const float*)d_in[25];
  const float* oe_b1   = (const float*)d_in[26];
  const float* oe_W2   = (const float*)d_in[27];
  const float* oe_b2   = (const float*)d_in[28];
  const float* ln_W1   = (const float*)d_in[29];
  const float* ln_b1   = (const float*)d_in[30];
  const float* ln_W2   = (const float*)d_in[31];
  const float* ln_b2   = (const float*)d_in[32];
  const float* le_W1   = (const float*)d_in[33];
  const float* le_b1   = (const float*)d_in[34];
  const float* le_W2   = (const float*)d_in[35];
  const float* le_b2   = (const float*)d_in[36];

  const int B = 8192;
  float* out_edge = (float*)d_out;
  float* out_node = out_edge + (size_t)B * 900;
  float* out_mu   = out_node + (size_t)B * 1920;
  float* out_lv   = out_mu + (size_t)B * 256;

  // ---- workspace carve ----
  char* base = (char*)d_ws;
  size_t off = 0;
  auto takeB = [&](size_t elems) -> u16* {
    u16* p = (u16*)(base + off);
    off = (off + elems * 2 + 255) & ~(size_t)255;
    return p;
  };
  auto takeF = [&](size_t elems) -> float* {
    float* p = (float*)(base + off);
    off = (off + elems * 4 + 255) & ~(size_t)255;
    return p;
  };
  u16* wEncH  = takeB(2048 * 1024);
  u16* wMulvH = takeB(512 * 2048);
  u16* wDec1H = takeB(2048 * 256);
  u16* wDec2H = takeB(2944 * 2048);
  u16* wO1H   = takeB(1024 * 1024);
  u16* wL1H   = takeB(1024 * 1024);
  u16* wO2H   = takeB(128 * 1024);
  u16* wL2H   = takeB(128 * 1024);
  u16* aXh = takeB((size_t)B * 1024); u16* aXl = takeB((size_t)B * 1024);
  u16* aOLh = takeB((size_t)2 * B * 1024);          // [16384,1024]: opt | log
  u16* aOh = aOLh;
  u16* aLh = aOLh + (size_t)B * 1024;
  u16* aHh = takeB((size_t)B * 2048); u16* aHl = takeB((size_t)B * 2048);
  u16* aZh = takeB((size_t)B * 256);  u16* aZl = takeB((size_t)B * 256);
  u16* aTh = takeB((size_t)2 * B * 1024);           // [16384,1024] tanh out
  float* logitsO = takeF((size_t)B * 65);
  float* logitsL = takeF((size_t)B * 90);
  float* nsc = takeF((size_t)B * 10);
  float* esc = takeF((size_t)B * 55);
  float* bn1sc = takeF(2048); float* bn1sh = takeF(2048);
  float* bn2sc = takeF(2048); float* bn2sh = takeF(2048);
  float* bias_mulv = takeF(512);
  float* bias_o1 = takeF(1024);
  float* bias_l1 = takeF(1024);
  float* bias_o2 = takeF(65);
  float* bias_l2 = takeF(90);

  // ---- prep: BN fold + bias concats, single launch ----
  PrepArgs pa;
  pa.bn1_g = bn1_g; pa.bn1_b = bn1_b; pa.bn1_m = bn1_m; pa.bn1_v = bn1_v;
  pa.bn2_g = bn2_g; pa.bn2_b = bn2_b; pa.bn2_m = bn2_m; pa.bn2_v = bn2_v;
  pa.mu_b = mu_b; pa.lv_b = lv_b;
  pa.on_b1 = on_b1; pa.oe_b1 = oe_b1; pa.ln_b1 = ln_b1; pa.le_b1 = le_b1;
  pa.on_b2 = on_b2; pa.oe_b2 = oe_b2; pa.ln_b2 = ln_b2; pa.le_b2 = le_b2;
  pa.bn1sc = bn1sc; pa.bn1sh = bn1sh; pa.bn2sc = bn2sc; pa.bn2sh = bn2sh;
  pa.bias_mulv = bias_mulv; pa.bias_o1 = bias_o1; pa.bias_l1 = bias_l1;
  pa.bias_o2 = bias_o2; pa.bias_l2 = bias_l2;
  prep_k<<<27, 256, 0, stream>>>(pa);

  // ---- input conversions, single launch ----
  conv3<<<24576, 256, 0, stream>>>(x, optical, logx, aXh, aXl, aOh, aLh);

  // ---- ALL weight transposes, single launch (job table) ----
  WTJobs wj;
  int blk = 0;
  auto addjob = [&](int idx, const float* src, u16* dh, int K, int N, int Npad) {
    wj.j[idx] = WTJob{src, dh, K, N, K / 32, blk};
    blk += (K / 32) * (Npad / 32);
  };
  addjob(0, enc_W,  wEncH,  1024, 2048, 2048);
  addjob(1, mu_W,   wMulvH, 2048, 256, 256);
  addjob(2, lv_W,   wMulvH + (size_t)256 * 2048, 2048, 256, 256);
  addjob(3, dec_W1, wDec1H, 256, 2048, 2048);
  addjob(4, dec_W2, wDec2H, 2048, 2820, 2944);
  addjob(5, on_W1,  wO1H,                        1024, 512, 512);
  addjob(6, oe_W1,  wO1H + (size_t)512 * 1024,   1024, 512, 512);
  addjob(7, ln_W1,  wL1H,                        1024, 512, 512);
  addjob(8, le_W1,  wL1H + (size_t)512 * 1024,   1024, 512, 512);
  conv_wT_all<<<blk, dim3(32, 8), 0, stream>>>(wj);
  conv_w2bd<<<512, 256, 0, stream>>>(on_W2, 10, oe_W2, 55, wO2H);
  conv_w2bd<<<512, 256, 0, stream>>>(ln_W2, 12, le_W2, 78, wL2H);

  EpParams p;

  // ---- encode: h1 = BN(ReLU(x @ enc_W + enc_b)) [NM=2: hh + lh] ----
  p = EpParams{};
  p.bias = enc_b; p.bnsc = bn1sc; p.bnsh = bn1sh;
  p.dhi = aHh; p.dlo = aHl; p.dstride = 2048;
  gemm_k<0, 2, true><<<dim3(64, 16), 256, 0, stream>>>(
      aXh, aXl, 1024, wEncH, nullptr, 1024, 2048, p);

  // ---- mu | logvar (concat N=512) [NM=2]; mu also -> z hi/lo ----
  p = EpParams{};
  p.bias = bias_mulv; p.f32a = out_mu; p.f32b = out_lv;
  p.dhi = aZh; p.dlo = aZl; p.dstride = 256;
  gemm_k<1, 2, false><<<dim3(64, 4), 256, 0, stream>>>(
      aHh, aHl, 2048, wMulvH, nullptr, 2048, 512, p);

  // ---- decode1: h2 = BN(ReLU(z @ dec_W1 + dec_b1)) [NM=2, hi-only store] ----
  p = EpParams{};
  p.bias = dec_b1; p.bnsc = bn2sc; p.bnsh = bn2sh;
  p.dhi = aHh; p.dlo = nullptr; p.dstride = 2048;
  gemm_k<0, 2, false><<<dim3(64, 16), 256, 0, stream>>>(
      aZh, aZl, 256, wDec1H, nullptr, 256, 2048, p);

  // ---- attn L1 merged: tanh([opt;log] @ {W1o|W1l}) [M=16384, NM=1] ----
  p = EpParams{};
  p.bias = bias_o1; p.bias2 = bias_l1; p.b2 = wL1H;
  p.dhi = aTh; p.dstride = 1024;
  gemm_k<2, 1, false><<<dim3(128, 8), 256, 0, stream>>>(
      aOLh, nullptr, 1024, wO1H, nullptr, 1024, 1024, p);

  // ---- attn L2 merged: logits [M=16384, NM=1, half-select B] ----
  p = EpParams{};
  p.bias = bias_o2; p.bias2 = bias_l2; p.b2 = wL2H;
  p.f32a = logitsO; p.f32b = logitsL;
  gemm_k<5, 1, false><<<dim3(128, 1), 256, 0, stream>>>(
      aTh, nullptr, 1024, wO2H, nullptr, 1024, 128, p);

  // ---- double softmax -> combined scales ----
  softmax_combine<<<32, 256, 0, stream>>>(logitsO, logitsL, nsc, esc);

  // ---- decode2 + fused attention scaling [NM=1] ----
  p = EpParams{};
  p.bias = dec_b2; p.nscale = nsc; p.escale = esc;
  p.f32a = out_edge; p.f32b = out_node;
  gemm_k<4, 1, false><<<dim3(64, 23), 256, 0, stream>>>(
      aHh, nullptr, 2048, wDec2H, nullptr, 2048, 2820, p);
}

// Round 8
// 773.129 us; speedup vs baseline: 1.1383x; 1.0167x over previous
//
#include <hip/hip_runtime.h>

using u16 = unsigned short;
using u32 = unsigned int;

typedef __attribute__((ext_vector_type(8))) short bf16x8;
typedef __attribute__((ext_vector_type(4))) float f32x4;

#define MFMA16 __builtin_amdgcn_mfma_f32_16x16x32_bf16

// ---------- fp32 <-> bf16 hi/lo split helpers ----------
__device__ __forceinline__ u16 f2bf(float f) {
  u32 u = __float_as_uint(f);
  u += 0x7fffu + ((u >> 16) & 1u);   // RNE
  return (u16)(u >> 16);
}
__device__ __forceinline__ float bf2f(u16 h) { return __uint_as_float(((u32)h) << 16); }

// async global->LDS, 16B per lane; LDS dest is wave-uniform base + lane*16
__device__ __forceinline__ void gld16(const u16* g, u16* s) {
  __builtin_amdgcn_global_load_lds((const __attribute__((address_space(1))) u32*)g,
                                   (__attribute__((address_space(3))) u32*)s, 16, 0, 0);
}

struct EpParams {
  const float* bias;
  const float* bias2;      // second-half bias (merged attn)
  const u16* b2;           // second-half B (merged attn)
  const float* bnsc;
  const float* bnsh;
  u16* dhi; u16* dlo; int dstride;
  float* f32a; float* f32b; int f32stride;
  const float* nscale; const float* escale;
};

struct GemmJob {
  const u16* Ah; const u16* Al; int lda;
  const u16* Bh;
  int K, N, ntm;           // tiles: tm = lbid % ntm, tn = lbid / ntm
  EpParams p;
};

// ---------------------------------------------------------------------------
// 128x128 m97-structure GEMM body (R3/R6-proven).
// A row-major [M,K] hi(/lo); B TRANSPOSED [Npad,K] hi, zero-padded.
// BK=32, 4 waves (2x2), each wave 64x64 = 4x4 frags of 16x16.
// NM: 1 = A_h*B_h ; 2 = + A_l*B_h
// EP: 0=BN(ReLU)(+SLO hilo)  1=mu/lv  2=tanh merged (B/bias by tm-half)
//     4=dec2+fused attn scaling  5=merged attn L2 logits
// ---------------------------------------------------------------------------
template<int EP, int NM, bool SLO>
__device__ __forceinline__ void gemm_body(const GemmJob& J, int lbid,
                                          u16* sAh, u16* sBh, u16* sAl) {
  const EpParams& p = J.p;
  const int t = threadIdx.x;
  const int lane = t & 63, wid = t >> 6;
  const int tm = lbid % J.ntm, tn = lbid / J.ntm;
  const int K = J.K, lda = J.lda;

  const u16* BhS = J.Bh;
  const float* bias = p.bias;
  if constexpr (EP == 2 || EP == 5) {
    if (tm >= (J.ntm >> 1)) { BhS = p.b2; bias = p.bias2; }
  }

  const int rp = t >> 2, sp = t & 3;
  const int rl = (rp & ~1) | ((rp & 1) ^ ((rp >> 2) & 1));
  const int sl = sp ^ (rl & 3);
  const u16* pAh = J.Ah + (size_t)(tm * 128 + rl) * (size_t)lda + sl * 8;
  const u16* pBh = BhS + (size_t)(tn * 128 + rl) * (size_t)K + sl * 8;
  const u16* pAl = (NM >= 2) ? J.Al + (size_t)(tm * 128 + rl) * (size_t)lda + sl * 8 : pAh;
  const size_t aStep = (size_t)64 * (size_t)lda;
  const size_t bStep = (size_t)64 * (size_t)K;

  f32x4 acc[4][4];
#pragma unroll
  for (int m = 0; m < 4; m++)
#pragma unroll
    for (int n = 0; n < 4; n++) acc[m][n] = f32x4{0.f, 0.f, 0.f, 0.f};

  const int fr = lane & 15, fg = lane >> 4;
  const int wm = wid >> 1, wn = wid & 1;

  for (int kk = 0; kk < K; kk += 32) {
    gld16(pAh + kk,          sAh + wid * 512);
    gld16(pAh + aStep + kk,  sAh + 2048 + wid * 512);
    gld16(pBh + kk,          sBh + wid * 512);
    gld16(pBh + bStep + kk,  sBh + 2048 + wid * 512);
    if constexpr (NM >= 2) {
      gld16(pAl + kk,         sAl + wid * 512);
      gld16(pAl + aStep + kk, sAl + 2048 + wid * 512);
    }
    __syncthreads();

    bf16x8 a_h[4], b_h[4], a_l[4];
#pragma unroll
    for (int f = 0; f < 4; f++) {
      const int ar = wm * 64 + f * 16 + fr;
      const int br = wn * 64 + f * 16 + fr;
      a_h[f] = *(const bf16x8*)&sAh[(ar * 32 + fg * 8) ^ ((ar & 7) << 3)];
      b_h[f] = *(const bf16x8*)&sBh[(br * 32 + fg * 8) ^ ((br & 7) << 3)];
      if constexpr (NM >= 2) a_l[f] = *(const bf16x8*)&sAl[(ar * 32 + fg * 8) ^ ((ar & 7) << 3)];
    }
#pragma unroll
    for (int m = 0; m < 4; m++)
#pragma unroll
      for (int n = 0; n < 4; n++) {
        if constexpr (NM >= 2)
          acc[m][n] = MFMA16(a_l[m], b_h[n], acc[m][n], 0, 0, 0);
        acc[m][n] = MFMA16(a_h[m], b_h[n], acc[m][n], 0, 0, 0);
      }
    __syncthreads();
  }

  // epilogue: C/D layout col=lane&15, row=4*(lane>>4)+reg [m89-verified]
  const int rowb = tm * 128 + wm * 64;
  const int colb = tn * 128 + wn * 64;
#pragma unroll
  for (int n = 0; n < 4; n++) {
    const int col = colb + n * 16 + fr;
#pragma unroll
    for (int m = 0; m < 4; m++) {
#pragma unroll
      for (int r = 0; r < 4; r++) {
        const int row = rowb + m * 16 + fg * 4 + r;
        float val = acc[m][n][r];
        if constexpr (EP == 0) {          // bias -> relu -> bn -> store
          val += bias[col];
          val = fmaxf(val, 0.f);
          val = val * p.bnsc[col] + p.bnsh[col];
          u16 h = f2bf(val);
          p.dhi[(size_t)row * p.dstride + col] = h;
          if constexpr (SLO)
            p.dlo[(size_t)row * p.dstride + col] = f2bf(val - bf2f(h));
        } else if constexpr (EP == 1) {   // mu (fp32 + hilo z) | logvar (fp32)
          val += bias[col];
          if (col < 256) {
            p.f32a[(size_t)row * 256 + col] = val;
            u16 h = f2bf(val);
            p.dhi[(size_t)row * 256 + col] = h;
            p.dlo[(size_t)row * 256 + col] = f2bf(val - bf2f(h));
          } else {
            p.f32b[(size_t)row * 256 + (col - 256)] = val;
          }
        } else if constexpr (EP == 2) {   // tanh -> bf16, merged halves
          val = tanhf(val + bias[col]);
          p.dhi[(size_t)row * p.dstride + col] = f2bf(val);
        } else if constexpr (EP == 5) {   // merged attn L2 logits
          if (tm < 64) {
            if (col < 65) p.f32a[(size_t)row * 65 + col] = val + bias[col];
          } else {
            if (col < 90) p.f32b[(size_t)(row - 8192) * 90 + col] = val + bias[col];
          }
        } else {                          // EP==4: dec2 -> scaled edge/node out
          if (col < J.N) {
            val += bias[col];
            if (col < 900) {
              int rr = col / 30, cc = col - rr * 30;
              float s = 1.f;
              if (rr >= 20 && cc >= 20 && rr <= cc) {
                int i0 = rr - 20, j0 = cc - 20;
                int k = i0 * 10 - ((i0 * (i0 - 1)) >> 1) + (j0 - i0);
                s = p.escale[(size_t)row * 55 + k];
              }
              p.f32a[(size_t)row * 900 + col] = val * s;
            } else {
              int tc = col - 900, rr = tc >> 6;
              float s = (rr >= 20) ? p.nscale[(size_t)row * 10 + (rr - 20)] : 1.f;
              p.f32b[(size_t)row * 1920 + tc] = val * s;
            }
          }
        }
      }
    }
  }
}

// ---------- standalone GEMM (dec2): 16 KB LDS, occupancy 3 ----------
template<int EP, int NM, bool SLO>
__global__ __launch_bounds__(256, (NM == 1) ? 3 : 2) void gemm_k(GemmJob J) {
  __shared__ __align__(16) u16 sAh[4096], sBh[4096];
  gemm_body<EP, NM, SLO>(J, blockIdx.x, sAh, sBh, sAh /*unused for NM=1*/);
}

// ---------- softmax args ----------
struct SmaxArgs { const float* lo; const float* ll; float* nsc; float* esc; };

__device__ __forceinline__ void softmax_body(const SmaxArgs& a, int b) {
  if (b >= 8192) return;
  const float* po = a.lo + (size_t)b * 65;
  const float* pl = a.ll + (size_t)b * 90;
  float mo = po[0];
  for (int i = 1; i < 10; i++) mo = fmaxf(mo, po[i]);
  float so = 0.f;
  for (int i = 0; i < 10; i++) so += expf(po[i] - mo);
  float ml = pl[0];
  for (int i = 1; i < 12; i++) ml = fmaxf(ml, pl[i]);
  float sl = 0.f;
  for (int i = 0; i < 12; i++) sl += expf(pl[i] - ml);
  float invn = 1.f / (so * sl);
  for (int i = 0; i < 10; i++)
    a.nsc[(size_t)b * 10 + i] = expf(po[i] - mo) * expf(pl[i] - ml) * invn;
  const float* qo = po + 10;
  const float* ql = pl + 12;
  float meo = qo[0];
  for (int i = 1; i < 55; i++) meo = fmaxf(meo, qo[i]);
  float seo = 0.f;
  for (int i = 0; i < 55; i++) seo += expf(qo[i] - meo);
  float mel = ql[0];
  for (int i = 1; i < 78; i++) mel = fmaxf(mel, ql[i]);
  float sel = 0.f;
  for (int i = 0; i < 78; i++) sel += expf(ql[i] - mel);
  float inve = 1.f / (seo * sel);
  for (int k = 0; k < 55; k++)
    a.esc[(size_t)b * 55 + k] = expf(qo[k] - meo) * expf(ql[k] - mel) * inve;
}

// ---------------------------------------------------------------------------
// Super kernel: jobA blocks [0,splitA), jobB [splitA,splitB), softmax rest.
// Bodies are block-uniform branches of the PROVEN gemm body — no sync-
// structure change; merging only improves CU fill of underfilled dispatches.
// ---------------------------------------------------------------------------
template<int EPA, int NMA, bool SLOA, int EPB, int NMB, bool SLOB, bool SMAX>
__global__ __launch_bounds__(256, 2) void super_k(
    int splitA, int splitB, GemmJob ja, GemmJob jb, SmaxArgs sm) {
  __shared__ __align__(16) u16 sAh[4096], sBh[4096], sAl[4096];
  const int bid = blockIdx.x;
  if (bid < splitA) {
    gemm_body<EPA, NMA, SLOA>(ja, bid, sAh, sBh, sAl);
  } else if (bid < splitB) {
    gemm_body<EPB, NMB, SLOB>(jb, bid - splitA, sAh, sBh, sAl);
  } else if constexpr (SMAX) {
    softmax_body(sm, (bid - splitB) * 256 + threadIdx.x);
  }
}

// ---------------------------------------------------------------------------
// Mega prep: conv3 + 9 weight transposes + 2 block-diags + BN/bias prep,
// all independent, one launch. Job picked by block range.
// ---------------------------------------------------------------------------
struct WTJob { const float* src; u16* dh; int K, N, nbx, blk0; };
struct PrepArgs {
  const float *bn1_g, *bn1_b, *bn1_m, *bn1_v, *bn2_g, *bn2_b, *bn2_m, *bn2_v;
  const float *mu_b, *lv_b, *on_b1, *oe_b1, *ln_b1, *le_b1, *on_b2, *oe_b2, *ln_b2, *le_b2;
  float *bn1sc, *bn1sh, *bn2sc, *bn2sh, *bias_mulv, *bias_o1, *bias_l1, *bias_o2, *bias_l2;
};
struct MegaArgs {
  // conv3
  const float *x, *opt, *lg; u16 *xh, *xl, *oh, *lh;
  // weight transposes
  WTJob wt[9];
  int wt_base, bd_base, prep_base;
  // block-diag W2s
  const float *onW2, *oeW2, *lnW2, *leW2; u16 *o2T, *l2T;
  // prep
  PrepArgs pr;
};

__global__ void mega_prep(MegaArgs A) {
  const int bid = blockIdx.x;
  const int t = threadIdx.x;
  if (bid < A.wt_base) {
    // ---- conv3: x -> hi/lo ; optical,log -> hi ----
    const int SEG = 8192 * 1024 / 4;
    int i = bid * 256 + t;
    if (i < SEG) {
      float4 v = ((const float4*)A.x)[i];
      ushort4 hh, ll;
      hh.x = f2bf(v.x); ll.x = f2bf(v.x - bf2f(hh.x));
      hh.y = f2bf(v.y); ll.y = f2bf(v.y - bf2f(hh.y));
      hh.z = f2bf(v.z); ll.z = f2bf(v.z - bf2f(hh.z));
      hh.w = f2bf(v.w); ll.w = f2bf(v.w - bf2f(hh.w));
      ((ushort4*)A.xh)[i] = hh;
      ((ushort4*)A.xl)[i] = ll;
    } else if (i < 2 * SEG) {
      int j = i - SEG;
      float4 v = ((const float4*)A.opt)[j];
      ushort4 hh;
      hh.x = f2bf(v.x); hh.y = f2bf(v.y); hh.z = f2bf(v.z); hh.w = f2bf(v.w);
      ((ushort4*)A.oh)[j] = hh;
    } else {
      int j = i - 2 * SEG;
      float4 v = ((const float4*)A.lg)[j];
      ushort4 hh;
      hh.x = f2bf(v.x); hh.y = f2bf(v.y); hh.z = f2bf(v.z); hh.w = f2bf(v.w);
      ((ushort4*)A.lh)[j] = hh;
    }
  } else if (bid < A.bd_base) {
    // ---- weight transpose: W[K,N] -> Wt hi [Npad,K], zero-pad ----
    __shared__ float tile[32][33];
    const int b = bid - A.wt_base;
    int ji = 0;
#pragma unroll
    for (int q = 1; q < 9; q++) if (b >= A.wt[q].blk0) ji = q;
    const WTJob jb = A.wt[ji];
    const int bl = b - jb.blk0;
    const int k0 = (bl % jb.nbx) * 32, n0 = (bl / jb.nbx) * 32;
    const int tx = t & 31, ty = t >> 5;
#pragma unroll
    for (int i = ty; i < 32; i += 8) {
      int n = n0 + tx;
      tile[i][tx] = (n < jb.N) ? jb.src[(size_t)(k0 + i) * jb.N + n] : 0.f;
    }
    __syncthreads();
#pragma unroll
    for (int i = ty; i < 32; i += 8) {
      int n = n0 + i, k = k0 + tx;
      jb.dh[(size_t)n * jb.K + k] = f2bf(tile[tx][i]);
    }
  } else if (bid < A.prep_base) {
    // ---- block-diag [Wa(512xNa); Wb(512xNb)] -> Wt [128,1024] ----
    const int lb = bid - A.bd_base;
    const bool second = lb >= 512;
    const int idx = (second ? lb - 512 : lb) * 256 + t;
    const float* Wa = second ? A.lnW2 : A.onW2;
    const float* Wb = second ? A.leW2 : A.oeW2;
    u16* Th = second ? A.l2T : A.o2T;
    const int Na = second ? 12 : 10, Nb = second ? 78 : 55;
    int n = idx >> 10, k = idx & 1023;
    float v = 0.f;
    if (n < Na) { if (k < 512) v = Wa[(size_t)k * Na + n]; }
    else if (n < Na + Nb) { if (k >= 512) v = Wb[(size_t)(k - 512) * Nb + (n - Na)]; }
    Th[idx] = f2bf(v);
  } else {
    // ---- BN folds + bias concats ----
    const PrepArgs& a = A.pr;
    int i = (bid - A.prep_base) * 256 + t;
    if (i < 2048) {
      float s = a.bn1_g[i] * rsqrtf(a.bn1_v[i] + 1e-5f);
      a.bn1sc[i] = s; a.bn1sh[i] = a.bn1_b[i] - a.bn1_m[i] * s;
    } else if (i < 4096) {
      int j = i - 2048;
      float s = a.bn2_g[j] * rsqrtf(a.bn2_v[j] + 1e-5f);
      a.bn2sc[j] = s; a.bn2sh[j] = a.bn2_b[j] - a.bn2_m[j] * s;
    } else if (i < 4608) {
      int j = i - 4096; a.bias_mulv[j] = (j < 256) ? a.mu_b[j] : a.lv_b[j - 256];
    } else if (i < 5632) {
      int j = i - 4608; a.bias_o1[j] = (j < 512) ? a.on_b1[j] : a.oe_b1[j - 512];
    } else if (i < 6656) {
      int j = i - 5632; a.bias_l1[j] = (j < 512) ? a.ln_b1[j] : a.le_b1[j - 512];
    } else if (i < 6721) {
      int j = i - 6656; a.bias_o2[j] = (j < 10) ? a.on_b2[j] : a.oe_b2[j - 10];
    } else if (i < 6811) {
      int j = i - 6721; a.bias_l2[j] = (j < 12) ? a.ln_b2[j] : a.le_b2[j - 12];
    }
  }
}

// ---------------------------------------------------------------------------
extern "C" void kernel_launch(void* const* d_in, const int* in_sizes, int n_in,
                              void* d_out, int out_size, void* d_ws, size_t ws_size,
                              hipStream_t stream) {
  const float* x       = (const float*)d_in[0];
  const float* optical = (const float*)d_in[1];
  const float* logx    = (const float*)d_in[2];
  const float* enc_W   = (const float*)d_in[3];
  const float* enc_b   = (const float*)d_in[4];
  const float* bn1_g   = (const float*)d_in[5];
  const float* bn1_b   = (const float*)d_in[6];
  const float* bn1_m   = (const float*)d_in[7];
  const float* bn1_v   = (const float*)d_in[8];
  const float* mu_W    = (const float*)d_in[9];
  const float* mu_b    = (const float*)d_in[10];
  const float* lv_W    = (const float*)d_in[11];
  const float* lv_b    = (const float*)d_in[12];
  const float* dec_W1  = (const float*)d_in[13];
  const float* dec_b1  = (const float*)d_in[14];
  const float* bn2_g   = (const float*)d_in[15];
  const float* bn2_b   = (const float*)d_in[16];
  const float* bn2_m   = (const float*)d_in[17];
  const float* bn2_v   = (const float*)d_in[18];
  const float* dec_W2  = (const float*)d_in[19];
  const float* dec_b2  = (const float*)d_in[20];
  const float* on_W1   = (const float*)d_in[21];
  const float* on_b1   = (const float*)d_in[22];
  const float* on_W2   = (const float*)d_in[23];
  const float* on_b2   = (const float*)d_in[24];
  const float* oe_W1   = (const float*)d_in[25];
  const float* oe_b1   = (const float*)d_in[26];
  const float* oe_W2   = (const float*)d_in[27];
  const float* oe_b2   = (const float*)d_in[28];
  const float* ln_W1   = (const float*)d_in[29];
  const float* ln_b1   = (const float*)d_in[30];
  const float* ln_W2   = (const float*)d_in[31];
  const float* ln_b2   = (const float*)d_in[32];
  const float* le_W1   = (const float*)d_in[33];
  const float* le_b1   = (const float*)d_in[34];
  const float* le_W2   = (const float*)d_in[35];
  const float* le_b2   = (const float*)d_in[36];

  const int B = 8192;
  float* out_edge = (float*)d_out;
  float* out_node = out_edge + (size_t)B * 900;
  float* out_mu   = out_node + (size_t)B * 1920;
  float* out_lv   = out_mu + (size_t)B * 256;

  // ---- workspace carve ----
  char* base = (char*)d_ws;
  size_t off = 0;
  auto takeB = [&](size_t elems) -> u16* {
    u16* p = (u16*)(base + off);
    off = (off + elems * 2 + 255) & ~(size_t)255;
    return p;
  };
  auto takeF = [&](size_t elems) -> float* {
    float* p = (float*)(base + off);
    off = (off + elems * 4 + 255) & ~(size_t)255;
    return p;
  };
  u16* wEncH  = takeB(2048 * 1024);
  u16* wMulvH = takeB(512 * 2048);
  u16* wDec1H = takeB(2048 * 256);
  u16* wDec2H = takeB(2944 * 2048);
  u16* wO1H   = takeB(1024 * 1024);
  u16* wL1H   = takeB(1024 * 1024);
  u16* wO2H   = takeB(128 * 1024);
  u16* wL2H   = takeB(128 * 1024);
  u16* aXh = takeB((size_t)B * 1024); u16* aXl = takeB((size_t)B * 1024);
  u16* aOLh = takeB((size_t)2 * B * 1024);          // [16384,1024]: opt | log
  u16* aOh = aOLh;
  u16* aLh = aOLh + (size_t)B * 1024;
  u16* aHh = takeB((size_t)B * 2048); u16* aHl = takeB((size_t)B * 2048);
  u16* aZh = takeB((size_t)B * 256);  u16* aZl = takeB((size_t)B * 256);
  u16* aTh = takeB((size_t)2 * B * 1024);           // [16384,1024] tanh out
  float* logitsO = takeF((size_t)B * 65);
  float* logitsL = takeF((size_t)B * 90);
  float* nsc = takeF((size_t)B * 10);
  float* esc = takeF((size_t)B * 55);
  float* bn1sc = takeF(2048); float* bn1sh = takeF(2048);
  float* bn2sc = takeF(2048); float* bn2sh = takeF(2048);
  float* bias_mulv = takeF(512);
  float* bias_o1 = takeF(1024);
  float* bias_l1 = takeF(1024);
  float* bias_o2 = takeF(65);
  float* bias_l2 = takeF(90);

  // ---- launch 1: mega prep (conv3 + 9 wT + 2 bd + BN/bias) ----
  MegaArgs ma;
  ma.x = x; ma.opt = optical; ma.lg = logx;
  ma.xh = aXh; ma.xl = aXl; ma.oh = aOh; ma.lh = aLh;
  int blk = 0;
  auto addjob = [&](int idx, const float* src, u16* dh, int K, int N, int Npad) {
    ma.wt[idx] = WTJob{src, dh, K, N, K / 32, blk};
    blk += (K / 32) * (Npad / 32);
  };
  addjob(0, enc_W,  wEncH,  1024, 2048, 2048);
  addjob(1, mu_W,   wMulvH, 2048, 256, 256);
  addjob(2, lv_W,   wMulvH + (size_t)256 * 2048, 2048, 256, 256);
  addjob(3, dec_W1, wDec1H, 256, 2048, 2048);
  addjob(4, dec_W2, wDec2H, 2048, 2820, 2944);
  addjob(5, on_W1,  wO1H,                        1024, 512, 512);
  addjob(6, oe_W1,  wO1H + (size_t)512 * 1024,   1024, 512, 512);
  addjob(7, ln_W1,  wL1H,                        1024, 512, 512);
  addjob(8, le_W1,  wL1H + (size_t)512 * 1024,   1024, 512, 512);
  const int CONV3_BLOCKS = 24576;
  ma.wt_base = CONV3_BLOCKS;
  ma.bd_base = CONV3_BLOCKS + blk;
  ma.prep_base = ma.bd_base + 1024;
  ma.onW2 = on_W2; ma.oeW2 = oe_W2; ma.lnW2 = ln_W2; ma.leW2 = le_W2;
  ma.o2T = wO2H; ma.l2T = wL2H;
  PrepArgs& pa = ma.pr;
  pa.bn1_g = bn1_g; pa.bn1_b = bn1_b; pa.bn1_m = bn1_m; pa.bn1_v = bn1_v;
  pa.bn2_g = bn2_g; pa.bn2_b = bn2_b; pa.bn2_m = bn2_m; pa.bn2_v = bn2_v;
  pa.mu_b = mu_b; pa.lv_b = lv_b;
  pa.on_b1 = on_b1; pa.oe_b1 = oe_b1; pa.ln_b1 = ln_b1; pa.le_b1 = le_b1;
  pa.on_b2 = on_b2; pa.oe_b2 = oe_b2; pa.ln_b2 = ln_b2; pa.le_b2 = le_b2;
  pa.bn1sc = bn1sc; pa.bn1sh = bn1sh; pa.bn2sc = bn2sc; pa.bn2sh = bn2sh;
  pa.bias_mulv = bias_mulv; pa.bias_o1 = bias_o1; pa.bias_l1 = bias_l1;
  pa.bias_o2 = bias_o2; pa.bias_l2 = bias_l2;
  mega_prep<<<ma.prep_base + 27, 256, 0, stream>>>(ma);

  SmaxArgs smnull{nullptr, nullptr, nullptr, nullptr};
  GemmJob jnull{};

  // ---- launch 2: super1 = enc (NM=2, EP0+SLO) || attn L1 (NM=1, EP2) ----
  GemmJob jEnc;
  jEnc.Ah = aXh; jEnc.Al = aXl; jEnc.lda = 1024; jEnc.Bh = wEncH;
  jEnc.K = 1024; jEnc.N = 2048; jEnc.ntm = 64;
  jEnc.p = EpParams{};
  jEnc.p.bias = enc_b; jEnc.p.bnsc = bn1sc; jEnc.p.bnsh = bn1sh;
  jEnc.p.dhi = aHh; jEnc.p.dlo = aHl; jEnc.p.dstride = 2048;
  GemmJob jA1;
  jA1.Ah = aOLh; jA1.Al = nullptr; jA1.lda = 1024; jA1.Bh = wO1H;
  jA1.K = 1024; jA1.N = 1024; jA1.ntm = 128;
  jA1.p = EpParams{};
  jA1.p.bias = bias_o1; jA1.p.bias2 = bias_l1; jA1.p.b2 = wL1H;
  jA1.p.dhi = aTh; jA1.p.dstride = 1024;
  super_k<0, 2, true, 2, 1, false, false><<<1024 + 1024, 256, 0, stream>>>(
      1024, 2048, jEnc, jA1, smnull);

  // ---- launch 3: super2 = mu|logvar (NM=2, EP1) || attn L2 (NM=1, EP5) ----
  GemmJob jMulv;
  jMulv.Ah = aHh; jMulv.Al = aHl; jMulv.lda = 2048; jMulv.Bh = wMulvH;
  jMulv.K = 2048; jMulv.N = 512; jMulv.ntm = 64;
  jMulv.p = EpParams{};
  jMulv.p.bias = bias_mulv; jMulv.p.f32a = out_mu; jMulv.p.f32b = out_lv;
  jMulv.p.dhi = aZh; jMulv.p.dlo = aZl; jMulv.p.dstride = 256;
  GemmJob jA2;
  jA2.Ah = aTh; jA2.Al = nullptr; jA2.lda = 1024; jA2.Bh = wO2H;
  jA2.K = 1024; jA2.N = 128; jA2.ntm = 128;
  jA2.p = EpParams{};
  jA2.p.bias = bias_o2; jA2.p.bias2 = bias_l2; jA2.p.b2 = wL2H;
  jA2.p.f32a = logitsO; jA2.p.f32b = logitsL;
  super_k<1, 2, false, 5, 1, false, false><<<256 + 128, 256, 0, stream>>>(
      256, 384, jMulv, jA2, smnull);

  // ---- launch 4: super3 = dec1 (NM=2, EP0 hi-only) + softmax tail ----
  GemmJob jD1;
  jD1.Ah = aZh; jD1.Al = aZl; jD1.lda = 256; jD1.Bh = wDec1H;
  jD1.K = 256; jD1.N = 2048; jD1.ntm = 64;
  jD1.p = EpParams{};
  jD1.p.bias = dec_b1; jD1.p.bnsc = bn2sc; jD1.p.bnsh = bn2sh;
  jD1.p.dhi = aHh; jD1.p.dlo = nullptr; jD1.p.dstride = 2048;
  SmaxArgs sm{logitsO, logitsL, nsc, esc};
  super_k<0, 2, false, 0, 1, false, true><<<1024 + 32, 256, 0, stream>>>(
      1024, 1024, jD1, jnull, sm);

  // ---- launch 5: dec2 + fused attention scaling (NM=1, EP4) ----
  GemmJob jD2;
  jD2.Ah = aHh; jD2.Al = nullptr; jD2.lda = 2048; jD2.Bh = wDec2H;
  jD2.K = 2048; jD2.N = 2820; jD2.ntm = 64;
  jD2.p = EpParams{};
  jD2.p.bias = dec_b2; jD2.p.nscale = nsc; jD2.p.escale = esc;
  jD2.p.f32a = out_edge; jD2.p.f32b = out_node;
  gemm_k<4, 1, false><<<64 * 23, 256, 0, stream>>>(jD2);
}